// Round 1
// baseline (1182.859 us; speedup 1.0000x reference)
//
#include <hip/hip_runtime.h>
#include <hip/hip_bf16.h>

#define NN 50000
#define EE 800000
#define IN_DIM 128
#define HH 128
#define HEADS 4
#define CC 32
#define LL 3
#define NCLS 10
#define NGRAPH 64

__device__ inline float lrelu(float x) { return x > 0.f ? x : 0.2f * x; }

__device__ inline float wred_max(float v) {
#pragma unroll
    for (int m = 32; m >= 1; m >>= 1) v = fmaxf(v, __shfl_xor(v, m, 64));
    return v;
}
__device__ inline float wred_sum(float v) {
#pragma unroll
    for (int m = 32; m >= 1; m >>= 1) v += __shfl_xor(v, m, 64);
    return v;
}

// ---------------- GEMM: out[N,128] = A[N,128] @ W[128,128] (+ optional node-init epilogue)
template <int MODE>  // 0 = plain, 1 = add b_node + type_emb[node_types]
__global__ __launch_bounds__(256) void gemm128(
    const float* __restrict__ A, const float* __restrict__ W, float* __restrict__ out,
    const float* __restrict__ bias, const int* __restrict__ ntypes,
    const float* __restrict__ temb, int nrows) {
    int tid = threadIdx.x;
    int c = tid & 127;
    int rth = tid >> 7;
    int row0 = blockIdx.x * 32;
    float acc[16];
#pragma unroll
    for (int i = 0; i < 16; i++) acc[i] = 0.f;

    if (row0 + 32 <= nrows) {
        const float* Ab = A + (size_t)(row0 + rth) * 128;
        for (int k = 0; k < 128; k++) {
            float w = W[k * 128 + c];
#pragma unroll
            for (int i = 0; i < 16; i++) acc[i] += Ab[i * 256 + k] * w;
        }
    } else {
        // tail block: clamp row reads
        const float* Ap[16];
#pragma unroll
        for (int i = 0; i < 16; i++) {
            int row = row0 + rth + 2 * i;
            int rc = row < nrows ? row : (nrows - 1);
            Ap[i] = A + (size_t)rc * 128;
        }
        for (int k = 0; k < 128; k++) {
            float w = W[k * 128 + c];
#pragma unroll
            for (int i = 0; i < 16; i++) acc[i] += Ap[i][k] * w;
        }
    }

#pragma unroll
    for (int i = 0; i < 16; i++) {
        int row = row0 + rth + 2 * i;
        if (row < nrows) {
            float v = acc[i];
            if (MODE == 1) v += bias[c] + temb[ntypes[row] * 128 + c];
            out[(size_t)row * 128 + c] = v;
        }
    }
}

// ---------------- per-node attention scores s_src/s_dst [N,4]
__global__ __launch_bounds__(256) void attn_scores(
    const float* __restrict__ xh, const float* __restrict__ asrc,
    const float* __restrict__ adst, float* __restrict__ s_src,
    float* __restrict__ s_dst, int n) {
    int tid = threadIdx.x;
    int node = blockIdx.x * 2 + (tid >> 7);
    int c = tid & 127;
    if (node >= n) return;
    int h = c >> 5;
    int cc = c & 31;
    float v = xh[(size_t)node * 128 + c];
    float ps = v * asrc[h * 32 + cc];
    float pd = v * adst[h * 32 + cc];
#pragma unroll
    for (int m = 16; m >= 1; m >>= 1) {
        ps += __shfl_xor(ps, m, 64);
        pd += __shfl_xor(pd, m, 64);
    }
    if (cc == 0) {
        s_src[node * 4 + h] = ps;
        s_dst[node * 4 + h] = pd;
    }
}

// ---------------- CSR build
__global__ void count_edges(const int* __restrict__ dst, int* __restrict__ deg, int ne) {
    int i = blockIdx.x * blockDim.x + threadIdx.x;
    if (i < ne) atomicAdd(&deg[dst[i]], 1);
}

__global__ __launch_bounds__(1024) void scan_kernel(const int* __restrict__ cnt,
                                                    int* __restrict__ row_ptr, int n) {
    __shared__ int partial[1024];
    int tid = threadIdx.x;
    int chunk = (n + 1023) / 1024;
    int start = tid * chunk;
    int end = start + chunk;
    if (end > n) end = n;
    int s = 0;
    for (int i = start; i < end; i++) s += cnt[i];
    partial[tid] = s;
    __syncthreads();
    for (int off = 1; off < 1024; off <<= 1) {
        int v = (tid >= off) ? partial[tid - off] : 0;
        __syncthreads();
        partial[tid] += v;
        __syncthreads();
    }
    int excl = (tid == 0) ? 0 : partial[tid - 1];
    for (int i = start; i < end; i++) {
        row_ptr[i] = excl;
        excl += cnt[i];
    }
    if (tid == 1023) row_ptr[n] = partial[1023];
}

__global__ void fill_edges(const int* __restrict__ ei, const int* __restrict__ row_ptr,
                           int* __restrict__ fill, int* __restrict__ col, int ne) {
    int i = blockIdx.x * blockDim.x + threadIdx.x;
    if (i < ne) {
        int d = ei[ne + i];
        int pos = row_ptr[d] + atomicAdd(&fill[d], 1);
        col[pos] = ei[i];
    }
}

// ---------------- fused GAT aggregate + bias + layernorm + residual relu (in-place h)
__global__ __launch_bounds__(256) void gat_aggregate(
    const float* __restrict__ xh, const float* __restrict__ ssrc,
    const float* __restrict__ sdst, const int* __restrict__ row_ptr,
    const int* __restrict__ col, const float* __restrict__ bg,
    const float* __restrict__ lng, const float* __restrict__ lnb,
    float* __restrict__ h, int n) {
    int wid = threadIdx.x >> 6;
    int lane = threadIdx.x & 63;
    int node = blockIdx.x * 4 + wid;
    if (node >= n) return;

    int base = row_ptr[node];
    int deg = row_ptr[node + 1] - base;

    float4 sd = ((const float4*)sdst)[node];
    float4 ssf = ((const float4*)ssrc)[node];
    float es0 = lrelu(ssf.x + sd.x), es1 = lrelu(ssf.y + sd.y);
    float es2 = lrelu(ssf.z + sd.z), es3 = lrelu(ssf.w + sd.w);

    // phase 1: max per head (self-loop included)
    float m0 = es0, m1 = es1, m2 = es2, m3 = es3;
    for (int j = lane; j < deg; j += 64) {
        int s = col[base + j];
        float4 ss = ((const float4*)ssrc)[s];
        m0 = fmaxf(m0, lrelu(ss.x + sd.x));
        m1 = fmaxf(m1, lrelu(ss.y + sd.y));
        m2 = fmaxf(m2, lrelu(ss.z + sd.z));
        m3 = fmaxf(m3, lrelu(ss.w + sd.w));
    }
    m0 = wred_max(m0); m1 = wred_max(m1); m2 = wred_max(m2); m3 = wred_max(m3);

    // phase 2: exp-sum per head
    float z0, z1, z2, z3;
    if (lane == 0) {
        z0 = expf(es0 - m0); z1 = expf(es1 - m1);
        z2 = expf(es2 - m2); z3 = expf(es3 - m3);
    } else {
        z0 = z1 = z2 = z3 = 0.f;
    }
    for (int j = lane; j < deg; j += 64) {
        int s = col[base + j];
        float4 ss = ((const float4*)ssrc)[s];
        z0 += expf(lrelu(ss.x + sd.x) - m0);
        z1 += expf(lrelu(ss.y + sd.y) - m1);
        z2 += expf(lrelu(ss.z + sd.z) - m2);
        z3 += expf(lrelu(ss.w + sd.w) - m3);
    }
    z0 = wred_sum(z0); z1 = wred_sum(z1); z2 = wred_sum(z2); z3 = wred_sum(z3);
    float i0 = 1.f / (z0 + 1e-16f), i1 = 1.f / (z1 + 1e-16f);
    float i2 = 1.f / (z2 + 1e-16f), i3 = 1.f / (z3 + 1e-16f);

    // phase 3: weighted message accumulate; lane owns channels c1=lane, c2=lane+64
    int c1 = lane, c2 = lane + 64;
    int hsel = lane >> 5;  // 0/1
    float sdA = hsel ? sd.y : sd.x, sdB = hsel ? sd.w : sd.z;
    float mA = hsel ? m1 : m0, mB = hsel ? m3 : m2;
    float iA = hsel ? i1 : i0, iB = hsel ? i3 : i2;
    float esA = hsel ? es1 : es0, esB = hsel ? es3 : es2;

    float aS1 = expf(esA - mA) * iA;
    float aS2 = expf(esB - mB) * iB;
    float acc1 = aS1 * xh[(size_t)node * 128 + c1];
    float acc2 = aS2 * xh[(size_t)node * 128 + c2];

    for (int j = 0; j < deg; j++) {
        int s = col[base + j];  // wave-uniform broadcast
        float4 ss = ((const float4*)ssrc)[s];
        float sA = hsel ? ss.y : ss.x;
        float sB = hsel ? ss.w : ss.z;
        float a1 = expf(lrelu(sA + sdA) - mA) * iA;
        float a2 = expf(lrelu(sB + sdB) - mB) * iB;
        const float* xr = xh + (size_t)s * 128;
        acc1 += a1 * xr[c1];
        acc2 += a2 * xr[c2];
    }

    float o1 = acc1 + bg[c1];
    float o2 = acc2 + bg[c2];
    // layernorm over 128 channels
    float mu = wred_sum(o1 + o2) * (1.f / 128.f);
    float d1 = o1 - mu, d2 = o2 - mu;
    float var = wred_sum(d1 * d1 + d2 * d2) * (1.f / 128.f);
    float rs = rsqrtf(var + 1e-5f);
    float y1 = d1 * rs * lng[c1] + lnb[c1];
    float y2 = d2 * rs * lng[c2] + lnb[c2];
    float* hr = h + (size_t)node * 128;
    float r1 = y1 + hr[c1];
    float r2 = y2 + hr[c2];
    hr[c1] = fmaxf(r1, 0.f);
    hr[c2] = fmaxf(r2, 0.f);
}

// ---------------- mean pool (batch sorted -> run-length atomics)
__global__ __launch_bounds__(256) void pool_kernel(const float* __restrict__ h,
                                                   const int* __restrict__ batch,
                                                   float* __restrict__ sums,
                                                   int* __restrict__ cnts, int n) {
    int c = threadIdx.x & 127;
    int half = threadIdx.x >> 7;
    int n0 = blockIdx.x * 64;
    float acc = 0.f;
    int cur = -1;
    for (int idx = half; idx < 64; idx += 2) {
        int node = n0 + idx;
        if (node >= n) break;
        int g = batch[node];
        if (g != cur) {
            if (cur >= 0) atomicAdd(&sums[cur * 128 + c], acc);
            cur = g;
            acc = 0.f;
        }
        acc += h[(size_t)node * 128 + c];
    }
    if (cur >= 0) atomicAdd(&sums[cur * 128 + c], acc);

    if (c == 0) {
        int cnt = 0, curg = -1;
        for (int idx = half; idx < 64; idx += 2) {
            int node = n0 + idx;
            if (node >= n) break;
            int g = batch[node];
            if (g != curg) {
                if (curg >= 0) atomicAdd(&cnts[curg], cnt);
                curg = g;
                cnt = 0;
            }
            cnt++;
        }
        if (curg >= 0) atomicAdd(&cnts[curg], cnt);
    }
}

// ---------------- MLP head: one block per graph
__global__ __launch_bounds__(256) void head_kernel(
    const float* __restrict__ sums, const int* __restrict__ cnts,
    const float* __restrict__ W1, const float* __restrict__ b1,
    const float* __restrict__ W2, const float* __restrict__ b2,
    const float* __restrict__ W3, const float* __restrict__ b3,
    float* __restrict__ out) {
    __shared__ float hg[128], z1[256], z2[128];
    int g = blockIdx.x;
    int t = threadIdx.x;
    if (t < 128) hg[t] = sums[g * 128 + t] / fmaxf((float)cnts[g], 1.f);
    __syncthreads();
    {
        float acc = b1[t];
        for (int k = 0; k < 128; k++) acc += hg[k] * W1[k * 256 + t];
        z1[t] = fmaxf(acc, 0.f);
    }
    __syncthreads();
    if (t < 128) {
        float acc = b2[t];
        for (int k = 0; k < 256; k++) acc += z1[k] * W2[k * 128 + t];
        z2[t] = fmaxf(acc, 0.f);
    }
    __syncthreads();
    if (t < NCLS) {
        float acc = b3[t];
        for (int k = 0; k < 128; k++) acc += z2[k] * W3[k * NCLS + t];
        out[g * NCLS + t] = acc;
    }
}

extern "C" void kernel_launch(void* const* d_in, const int* in_sizes, int n_in,
                              void* d_out, int out_size, void* d_ws, size_t ws_size,
                              hipStream_t stream) {
    const float* x = (const float*)d_in[0];
    const int* ei = (const int*)d_in[1];
    const int* ntypes = (const int*)d_in[2];
    const int* batch = (const int*)d_in[3];
    const float* W_node = (const float*)d_in[4];
    const float* b_node = (const float*)d_in[5];
    const float* temb = (const float*)d_in[6];
    const float* W_gat = (const float*)d_in[7];
    const float* a_src = (const float*)d_in[8];
    const float* a_dst = (const float*)d_in[9];
    const float* b_gat = (const float*)d_in[10];
    const float* ln_g = (const float*)d_in[11];
    const float* ln_b = (const float*)d_in[12];
    const float* W1 = (const float*)d_in[13];
    const float* b1 = (const float*)d_in[14];
    const float* W2 = (const float*)d_in[15];
    const float* b2 = (const float*)d_in[16];
    const float* W3 = (const float*)d_in[17];
    const float* b3 = (const float*)d_in[18];
    float* out = (float*)d_out;

    char* ws = (char*)d_ws;
    size_t off = 0;
    auto alloc = [&](size_t bytes) {
        void* p = ws + off;
        off += (bytes + 255) & ~(size_t)255;
        return p;
    };
    float* h = (float*)alloc((size_t)NN * 128 * 4);
    float* xh = (float*)alloc((size_t)NN * 128 * 4);
    float* ssrc = (float*)alloc((size_t)NN * 4 * 4);
    float* sdst = (float*)alloc((size_t)NN * 4 * 4);
    int* rowp = (int*)alloc((size_t)(NN + 1) * 4);
    int* fillc = (int*)alloc((size_t)NN * 4);
    int* col = (int*)alloc((size_t)EE * 4);
    float* psum = (float*)alloc((size_t)NGRAPH * 128 * 4);
    int* pcnt = (int*)alloc((size_t)NGRAPH * 4);

    // ---- CSR build (per call; cheap)
    hipMemsetAsync(fillc, 0, (size_t)NN * 4, stream);
    hipMemsetAsync(psum, 0, (size_t)NGRAPH * 128 * 4, stream);
    hipMemsetAsync(pcnt, 0, (size_t)NGRAPH * 4, stream);
    count_edges<<<(EE + 255) / 256, 256, 0, stream>>>(ei + EE, fillc, EE);
    scan_kernel<<<1, 1024, 0, stream>>>(fillc, rowp, NN);
    hipMemsetAsync(fillc, 0, (size_t)NN * 4, stream);
    fill_edges<<<(EE + 255) / 256, 256, 0, stream>>>(ei, rowp, fillc, col, EE);

    // ---- node init: h = x@W_node + b_node + type_emb[node_types]
    int gemm_grid = (NN + 31) / 32;
    gemm128<1><<<gemm_grid, 256, 0, stream>>>(x, W_node, h, b_node, ntypes, temb, NN);

    for (int l = 0; l < LL; l++) {
        gemm128<0><<<gemm_grid, 256, 0, stream>>>(h, W_gat + (size_t)l * 128 * 128, xh,
                                                  nullptr, nullptr, nullptr, NN);
        attn_scores<<<(NN + 1) / 2, 256, 0, stream>>>(xh, a_src + l * HEADS * CC,
                                                      a_dst + l * HEADS * CC, ssrc, sdst, NN);
        gat_aggregate<<<(NN + 3) / 4, 256, 0, stream>>>(
            xh, ssrc, sdst, rowp, col, b_gat + l * 128, ln_g + l * 128, ln_b + l * 128, h, NN);
    }

    pool_kernel<<<(NN + 63) / 64, 256, 0, stream>>>(h, batch, psum, pcnt, NN);
    head_kernel<<<NGRAPH, 256, 0, stream>>>(psum, pcnt, W1, b1, W2, b2, W3, b3, out);
}

// Round 2
// 913.220 us; speedup vs baseline: 1.2953x; 1.2953x over previous
//
#include <hip/hip_runtime.h>
#include <hip/hip_bf16.h>

#define NN 50000
#define EE 800000
#define IN_DIM 128
#define HH 128
#define HEADS 4
#define CC 32
#define LL 3
#define NCLS 10
#define NGRAPH 64

__device__ inline float lrelu(float x) { return x > 0.f ? x : 0.2f * x; }

__device__ inline float wred_max(float v) {
#pragma unroll
    for (int m = 32; m >= 1; m >>= 1) v = fmaxf(v, __shfl_xor(v, m, 64));
    return v;
}
__device__ inline float wred_sum(float v) {
#pragma unroll
    for (int m = 32; m >= 1; m >>= 1) v += __shfl_xor(v, m, 64);
    return v;
}

__device__ inline float pick4(int h, float a, float b, float c, float d) {
    float ab = (h & 1) ? b : a;
    float cd = (h & 1) ? d : c;
    return (h & 2) ? cd : ab;
}

// ---------------- GEMM: out[N,128] = A[N,128] @ W[128,128] (+ optional node-init epilogue)
// 256 thr/block, BM=64. thread: column pair c2 (2 cols), 16 rows (rth + 4i).
template <int MODE>  // 0 = plain, 1 = add b_node + type_emb[node_types]
__global__ __launch_bounds__(256) void gemm128(
    const float* __restrict__ A, const float* __restrict__ W, float* __restrict__ out,
    const float* __restrict__ bias, const int* __restrict__ ntypes,
    const float* __restrict__ temb, int nrows) {
    int tid = threadIdx.x;
    int c2 = tid & 63;   // column-pair index: columns 2*c2, 2*c2+1
    int rth = tid >> 6;  // 0..3
    int row0 = blockIdx.x * 64;
    const float2* __restrict__ W2 = (const float2*)W;

    float2 acc[16];
#pragma unroll
    for (int i = 0; i < 16; i++) acc[i] = make_float2(0.f, 0.f);

    if (row0 + 64 <= nrows) {
        const float4* __restrict__ A4 = (const float4*)A + (size_t)(row0 + rth) * 32;
        for (int kk = 0; kk < 32; kk++) {
            float2 w0 = W2[(4 * kk + 0) * 64 + c2];
            float2 w1 = W2[(4 * kk + 1) * 64 + c2];
            float2 w2 = W2[(4 * kk + 2) * 64 + c2];
            float2 w3 = W2[(4 * kk + 3) * 64 + c2];
#pragma unroll
            for (int i = 0; i < 16; i++) {
                float4 av = A4[(size_t)i * 128 + kk];
                acc[i].x += av.x * w0.x + av.y * w1.x + av.z * w2.x + av.w * w3.x;
                acc[i].y += av.x * w0.y + av.y * w1.y + av.z * w2.y + av.w * w3.y;
            }
        }
    } else {
        const float4* __restrict__ A4p[16];
#pragma unroll
        for (int i = 0; i < 16; i++) {
            int row = row0 + rth + 4 * i;
            int rc = row < nrows ? row : (nrows - 1);
            A4p[i] = (const float4*)(A + (size_t)rc * 128);
        }
        for (int kk = 0; kk < 32; kk++) {
            float2 w0 = W2[(4 * kk + 0) * 64 + c2];
            float2 w1 = W2[(4 * kk + 1) * 64 + c2];
            float2 w2 = W2[(4 * kk + 2) * 64 + c2];
            float2 w3 = W2[(4 * kk + 3) * 64 + c2];
#pragma unroll
            for (int i = 0; i < 16; i++) {
                float4 av = A4p[i][kk];
                acc[i].x += av.x * w0.x + av.y * w1.x + av.z * w2.x + av.w * w3.x;
                acc[i].y += av.x * w0.y + av.y * w1.y + av.z * w2.y + av.w * w3.y;
            }
        }
    }

#pragma unroll
    for (int i = 0; i < 16; i++) {
        int row = row0 + rth + 4 * i;
        if (row < nrows) {
            float2 v = acc[i];
            if (MODE == 1) {
                int nt = ntypes[row];
                const float2* tb = (const float2*)(temb + (size_t)nt * 128);
                const float2* bb = (const float2*)bias;
                float2 t = tb[c2];
                float2 b = bb[c2];
                v.x += b.x + t.x;
                v.y += b.y + t.y;
            }
            ((float2*)(out + (size_t)row * 128))[c2] = v;
        }
    }
}

// ---------------- per-node attention scores s_src/s_dst [N,4]
__global__ __launch_bounds__(256) void attn_scores(
    const float* __restrict__ xh, const float* __restrict__ asrc,
    const float* __restrict__ adst, float* __restrict__ s_src,
    float* __restrict__ s_dst, int n) {
    int tid = threadIdx.x;
    int node = blockIdx.x * 2 + (tid >> 7);
    int c = tid & 127;
    if (node >= n) return;
    int h = c >> 5;
    int cc = c & 31;
    float v = xh[(size_t)node * 128 + c];
    float ps = v * asrc[h * 32 + cc];
    float pd = v * adst[h * 32 + cc];
#pragma unroll
    for (int m = 16; m >= 1; m >>= 1) {
        ps += __shfl_xor(ps, m, 64);
        pd += __shfl_xor(pd, m, 64);
    }
    if (cc == 0) {
        s_src[node * 4 + h] = ps;
        s_dst[node * 4 + h] = pd;
    }
}

// ---------------- CSR build
__global__ void count_edges(const int* __restrict__ dst, int* __restrict__ deg, int ne) {
    int i = blockIdx.x * blockDim.x + threadIdx.x;
    if (i < ne) atomicAdd(&deg[dst[i]], 1);
}

__global__ __launch_bounds__(1024) void scan_kernel(const int* __restrict__ cnt,
                                                    int* __restrict__ row_ptr, int n) {
    __shared__ int partial[1024];
    int tid = threadIdx.x;
    int chunk = (n + 1023) / 1024;
    int start = tid * chunk;
    int end = start + chunk;
    if (end > n) end = n;
    int s = 0;
    for (int i = start; i < end; i++) s += cnt[i];
    partial[tid] = s;
    __syncthreads();
    for (int off = 1; off < 1024; off <<= 1) {
        int v = (tid >= off) ? partial[tid - off] : 0;
        __syncthreads();
        partial[tid] += v;
        __syncthreads();
    }
    int excl = (tid == 0) ? 0 : partial[tid - 1];
    for (int i = start; i < end; i++) {
        row_ptr[i] = excl;
        excl += cnt[i];
    }
    if (tid == 1023) row_ptr[n] = partial[1023];
}

__global__ void fill_edges(const int* __restrict__ ei, const int* __restrict__ row_ptr,
                           int* __restrict__ fill, int* __restrict__ col, int ne) {
    int i = blockIdx.x * blockDim.x + threadIdx.x;
    if (i < ne) {
        int d = ei[ne + i];
        int pos = row_ptr[d] + atomicAdd(&fill[d], 1);
        col[pos] = ei[i];
    }
}

// ---------------- fused GAT aggregate + bias + layernorm + residual relu (in-place h)
// wave per node. Phase 3: lane = eg(0..3)*16 + g(0..15); lane owns 8 channels [g*8, g*8+8)
// of ONE head (head = g>>2), iterates edges 4-at-a-time (one per eg).
__global__ __launch_bounds__(256) void gat_aggregate(
    const float* __restrict__ xh, const float* __restrict__ ssrc,
    const float* __restrict__ sdst, const int* __restrict__ row_ptr,
    const int* __restrict__ col, const float* __restrict__ bg,
    const float* __restrict__ lng, const float* __restrict__ lnb,
    float* __restrict__ h, int n) {
    int wid = threadIdx.x >> 6;
    int lane = threadIdx.x & 63;
    int node = blockIdx.x * 4 + wid;
    if (node >= n) return;

    int base = row_ptr[node];
    int deg = row_ptr[node + 1] - base;

    float4 sd = ((const float4*)sdst)[node];
    float4 ssf = ((const float4*)ssrc)[node];
    float es0 = lrelu(ssf.x + sd.x), es1 = lrelu(ssf.y + sd.y);
    float es2 = lrelu(ssf.z + sd.z), es3 = lrelu(ssf.w + sd.w);

    // phase 1: max per head (self-loop included)
    float m0 = es0, m1 = es1, m2 = es2, m3 = es3;
    for (int j = lane; j < deg; j += 64) {
        int s = col[base + j];
        float4 ss = ((const float4*)ssrc)[s];
        m0 = fmaxf(m0, lrelu(ss.x + sd.x));
        m1 = fmaxf(m1, lrelu(ss.y + sd.y));
        m2 = fmaxf(m2, lrelu(ss.z + sd.z));
        m3 = fmaxf(m3, lrelu(ss.w + sd.w));
    }
    m0 = wred_max(m0); m1 = wred_max(m1); m2 = wred_max(m2); m3 = wred_max(m3);

    // phase 2: exp-sum per head
    float z0, z1, z2, z3;
    if (lane == 0) {
        z0 = expf(es0 - m0); z1 = expf(es1 - m1);
        z2 = expf(es2 - m2); z3 = expf(es3 - m3);
    } else {
        z0 = z1 = z2 = z3 = 0.f;
    }
    for (int j = lane; j < deg; j += 64) {
        int s = col[base + j];
        float4 ss = ((const float4*)ssrc)[s];
        z0 += expf(lrelu(ss.x + sd.x) - m0);
        z1 += expf(lrelu(ss.y + sd.y) - m1);
        z2 += expf(lrelu(ss.z + sd.z) - m2);
        z3 += expf(lrelu(ss.w + sd.w) - m3);
    }
    z0 = wred_sum(z0); z1 = wred_sum(z1); z2 = wred_sum(z2); z3 = wred_sum(z3);
    float i0 = 1.f / (z0 + 1e-16f), i1 = 1.f / (z1 + 1e-16f);
    float i2 = 1.f / (z2 + 1e-16f), i3 = 1.f / (z3 + 1e-16f);

    // phase 3: 4-edge-parallel weighted message accumulate
    int eg = lane >> 4;       // edge group 0..3
    int g = lane & 15;        // channel group; channels [g*8, g*8+8), one head
    int head = g >> 2;
    float sdH = pick4(head, sd.x, sd.y, sd.z, sd.w);
    float mH = pick4(head, m0, m1, m2, m3);
    float iH = pick4(head, i0, i1, i2, i3);
    float esH = pick4(head, es0, es1, es2, es3);

    float acc[8];
#pragma unroll
    for (int k = 0; k < 8; k++) acc[k] = 0.f;

    if (eg == 0) {  // self-loop, counted once
        float aS = expf(esH - mH) * iH;
        const float4* xr = (const float4*)(xh + (size_t)node * 128 + g * 8);
        float4 x0 = xr[0], x1 = xr[1];
        acc[0] += aS * x0.x; acc[1] += aS * x0.y; acc[2] += aS * x0.z; acc[3] += aS * x0.w;
        acc[4] += aS * x1.x; acc[5] += aS * x1.y; acc[6] += aS * x1.z; acc[7] += aS * x1.w;
    }

    int nit = (deg + 3) >> 2;
    for (int t = 0; t < nit; t++) {
        int j = t * 4 + eg;
        if (j < deg) {
            int s = col[base + j];
            float4 ss = ((const float4*)ssrc)[s];
            float sH = pick4(head, ss.x, ss.y, ss.z, ss.w);
            float a = expf(lrelu(sH + sdH) - mH) * iH;
            const float4* xr = (const float4*)(xh + (size_t)s * 128 + g * 8);
            float4 x0 = xr[0], x1 = xr[1];
            acc[0] += a * x0.x; acc[1] += a * x0.y; acc[2] += a * x0.z; acc[3] += a * x0.w;
            acc[4] += a * x1.x; acc[5] += a * x1.y; acc[6] += a * x1.z; acc[7] += a * x1.w;
        }
    }
    // reduce across the 4 edge groups (all replicas end up with full sums)
#pragma unroll
    for (int k = 0; k < 8; k++) {
        acc[k] += __shfl_xor(acc[k], 16, 64);
        acc[k] += __shfl_xor(acc[k], 32, 64);
    }

    // bias + layernorm (channels replicated 4x across wave -> divide wave sums by 4)
    const float4* bg4 = (const float4*)(bg + g * 8);
    float4 b0 = bg4[0], b1 = bg4[1];
    float o[8];
    o[0] = acc[0] + b0.x; o[1] = acc[1] + b0.y; o[2] = acc[2] + b0.z; o[3] = acc[3] + b0.w;
    o[4] = acc[4] + b1.x; o[5] = acc[5] + b1.y; o[6] = acc[6] + b1.z; o[7] = acc[7] + b1.w;

    float ls = 0.f;
#pragma unroll
    for (int k = 0; k < 8; k++) ls += o[k];
    float mu = wred_sum(ls) * (1.f / 512.f);
    float vs = 0.f;
#pragma unroll
    for (int k = 0; k < 8; k++) {
        o[k] -= mu;
        vs += o[k] * o[k];
    }
    float var = wred_sum(vs) * (1.f / 512.f);
    float rs = rsqrtf(var + 1e-5f);

    if (eg == 0) {
        const float4* lg4 = (const float4*)(lng + g * 8);
        const float4* lb4 = (const float4*)(lnb + g * 8);
        float4 g0 = lg4[0], g1 = lg4[1];
        float4 q0 = lb4[0], q1 = lb4[1];
        float* hr = h + (size_t)node * 128 + g * 8;
        float4* hr4 = (float4*)hr;
        float4 p0 = hr4[0], p1 = hr4[1];
        float4 y0, y1;
        y0.x = fmaxf(o[0] * rs * g0.x + q0.x + p0.x, 0.f);
        y0.y = fmaxf(o[1] * rs * g0.y + q0.y + p0.y, 0.f);
        y0.z = fmaxf(o[2] * rs * g0.z + q0.z + p0.z, 0.f);
        y0.w = fmaxf(o[3] * rs * g0.w + q0.w + p0.w, 0.f);
        y1.x = fmaxf(o[4] * rs * g1.x + q1.x + p1.x, 0.f);
        y1.y = fmaxf(o[5] * rs * g1.y + q1.y + p1.y, 0.f);
        y1.z = fmaxf(o[6] * rs * g1.z + q1.z + p1.z, 0.f);
        y1.w = fmaxf(o[7] * rs * g1.w + q1.w + p1.w, 0.f);
        hr4[0] = y0;
        hr4[1] = y1;
    }
}

// ---------------- mean pool (batch sorted -> run-length atomics)
__global__ __launch_bounds__(256) void pool_kernel(const float* __restrict__ h,
                                                   const int* __restrict__ batch,
                                                   float* __restrict__ sums,
                                                   int* __restrict__ cnts, int n) {
    int c = threadIdx.x & 127;
    int half = threadIdx.x >> 7;
    int n0 = blockIdx.x * 64;
    float acc = 0.f;
    int cur = -1;
    for (int idx = half; idx < 64; idx += 2) {
        int node = n0 + idx;
        if (node >= n) break;
        int g = batch[node];
        if (g != cur) {
            if (cur >= 0) atomicAdd(&sums[cur * 128 + c], acc);
            cur = g;
            acc = 0.f;
        }
        acc += h[(size_t)node * 128 + c];
    }
    if (cur >= 0) atomicAdd(&sums[cur * 128 + c], acc);

    if (c == 0) {
        int cnt = 0, curg = -1;
        for (int idx = half; idx < 64; idx += 2) {
            int node = n0 + idx;
            if (node >= n) break;
            int g = batch[node];
            if (g != curg) {
                if (curg >= 0) atomicAdd(&cnts[curg], cnt);
                curg = g;
                cnt = 0;
            }
            cnt++;
        }
        if (curg >= 0) atomicAdd(&cnts[curg], cnt);
    }
}

// ---------------- MLP head: one block per graph
__global__ __launch_bounds__(256) void head_kernel(
    const float* __restrict__ sums, const int* __restrict__ cnts,
    const float* __restrict__ W1, const float* __restrict__ b1,
    const float* __restrict__ W2, const float* __restrict__ b2,
    const float* __restrict__ W3, const float* __restrict__ b3,
    float* __restrict__ out) {
    __shared__ float hg[128], z1[256], z2[128];
    int g = blockIdx.x;
    int t = threadIdx.x;
    if (t < 128) hg[t] = sums[g * 128 + t] / fmaxf((float)cnts[g], 1.f);
    __syncthreads();
    {
        float acc = b1[t];
        for (int k = 0; k < 128; k++) acc += hg[k] * W1[k * 256 + t];
        z1[t] = fmaxf(acc, 0.f);
    }
    __syncthreads();
    if (t < 128) {
        float acc = b2[t];
        for (int k = 0; k < 256; k++) acc += z1[k] * W2[k * 128 + t];
        z2[t] = fmaxf(acc, 0.f);
    }
    __syncthreads();
    if (t < NCLS) {
        float acc = b3[t];
        for (int k = 0; k < 128; k++) acc += z2[k] * W3[k * NCLS + t];
        out[g * NCLS + t] = acc;
    }
}

extern "C" void kernel_launch(void* const* d_in, const int* in_sizes, int n_in,
                              void* d_out, int out_size, void* d_ws, size_t ws_size,
                              hipStream_t stream) {
    const float* x = (const float*)d_in[0];
    const int* ei = (const int*)d_in[1];
    const int* ntypes = (const int*)d_in[2];
    const int* batch = (const int*)d_in[3];
    const float* W_node = (const float*)d_in[4];
    const float* b_node = (const float*)d_in[5];
    const float* temb = (const float*)d_in[6];
    const float* W_gat = (const float*)d_in[7];
    const float* a_src = (const float*)d_in[8];
    const float* a_dst = (const float*)d_in[9];
    const float* b_gat = (const float*)d_in[10];
    const float* ln_g = (const float*)d_in[11];
    const float* ln_b = (const float*)d_in[12];
    const float* W1 = (const float*)d_in[13];
    const float* b1 = (const float*)d_in[14];
    const float* W2 = (const float*)d_in[15];
    const float* b2 = (const float*)d_in[16];
    const float* W3 = (const float*)d_in[17];
    const float* b3 = (const float*)d_in[18];
    float* out = (float*)d_out;

    char* ws = (char*)d_ws;
    size_t off = 0;
    auto alloc = [&](size_t bytes) {
        void* p = ws + off;
        off += (bytes + 255) & ~(size_t)255;
        return p;
    };
    float* h = (float*)alloc((size_t)NN * 128 * 4);
    float* xh = (float*)alloc((size_t)NN * 128 * 4);
    float* ssrc = (float*)alloc((size_t)NN * 4 * 4);
    float* sdst = (float*)alloc((size_t)NN * 4 * 4);
    int* rowp = (int*)alloc((size_t)(NN + 1) * 4);
    int* fillc = (int*)alloc((size_t)NN * 4);
    int* col = (int*)alloc((size_t)EE * 4);
    float* psum = (float*)alloc((size_t)NGRAPH * 128 * 4);
    int* pcnt = (int*)alloc((size_t)NGRAPH * 4);

    // ---- CSR build (per call)
    hipMemsetAsync(fillc, 0, (size_t)NN * 4, stream);
    hipMemsetAsync(psum, 0, (size_t)NGRAPH * 128 * 4, stream);
    hipMemsetAsync(pcnt, 0, (size_t)NGRAPH * 4, stream);
    count_edges<<<(EE + 255) / 256, 256, 0, stream>>>(ei + EE, fillc, EE);
    scan_kernel<<<1, 1024, 0, stream>>>(fillc, rowp, NN);
    hipMemsetAsync(fillc, 0, (size_t)NN * 4, stream);
    fill_edges<<<(EE + 255) / 256, 256, 0, stream>>>(ei, rowp, fillc, col, EE);

    // ---- node init: h = x@W_node + b_node + type_emb[node_types]
    int gemm_grid = (NN + 63) / 64;
    gemm128<1><<<gemm_grid, 256, 0, stream>>>(x, W_node, h, b_node, ntypes, temb, NN);

    for (int l = 0; l < LL; l++) {
        gemm128<0><<<gemm_grid, 256, 0, stream>>>(h, W_gat + (size_t)l * 128 * 128, xh,
                                                  nullptr, nullptr, nullptr, NN);
        attn_scores<<<(NN + 1) / 2, 256, 0, stream>>>(xh, a_src + l * HEADS * CC,
                                                      a_dst + l * HEADS * CC, ssrc, sdst, NN);
        gat_aggregate<<<(NN + 3) / 4, 256, 0, stream>>>(
            xh, ssrc, sdst, rowp, col, b_gat + l * 128, ln_g + l * 128, ln_b + l * 128, h, NN);
    }

    pool_kernel<<<(NN + 63) / 64, 256, 0, stream>>>(h, batch, psum, pcnt, NN);
    head_kernel<<<NGRAPH, 256, 0, stream>>>(psum, pcnt, W1, b1, W2, b2, W3, b3, out);
}

// Round 4
// 595.984 us; speedup vs baseline: 1.9847x; 1.5323x over previous
//
#include <hip/hip_runtime.h>
#include <hip/hip_bf16.h>

#define NN 50000
#define EE 800000
#define IN_DIM 128
#define HH 128
#define HEADS 4
#define CC 32
#define LL 3
#define NCLS 10
#define NGRAPH 64

using short8 = __attribute__((ext_vector_type(8))) short;
using f32x4 = __attribute__((ext_vector_type(4))) float;

__device__ inline float lrelu(float x) { return x > 0.f ? x : 0.2f * x; }

__device__ inline float bf2f(ushort u) {
    union { uint32_t i; float f; } c;
    c.i = ((uint32_t)u) << 16;
    return c.f;
}
__device__ inline ushort f2bf(float f) {
    union { float f; uint32_t i; } c;
    c.f = f;
    uint32_t x = c.i;
    uint32_t r = (x + 0x7fffu + ((x >> 16) & 1u)) >> 16;
    return (ushort)r;
}

__device__ inline float wred_sum(float v) {
#pragma unroll
    for (int m = 32; m >= 1; m >>= 1) v += __shfl_xor(v, m, 64);
    return v;
}

__device__ inline float pick4(int h, float a, float b, float c, float d) {
    float ab = (h & 1) ? b : a;
    float cd = (h & 1) ? d : c;
    return (h & 2) ? cd : ab;
}

// ---------------- x -> bf16 (6.4M elements, 8/thread)
__global__ __launch_bounds__(256) void convert_x(const float* __restrict__ x,
                                                 ushort* __restrict__ xb) {
    int u = blockIdx.x * 256 + threadIdx.x;  // ushort8 unit
    const float4* x4 = (const float4*)x;
    float4 f0 = x4[u * 2];
    float4 f1 = x4[u * 2 + 1];
    short8 o;
    o[0] = (short)f2bf(f0.x); o[1] = (short)f2bf(f0.y);
    o[2] = (short)f2bf(f0.z); o[3] = (short)f2bf(f0.w);
    o[4] = (short)f2bf(f1.x); o[5] = (short)f2bf(f1.y);
    o[6] = (short)f2bf(f1.z); o[7] = (short)f2bf(f1.w);
    ((short8*)xb)[u] = o;
}

// ---------------- weights -> W^T bf16, pre-swizzled (16B unit u ^= n&7)
// block b: 0 = W_node, 1..3 = W_gat[l]
__global__ __launch_bounds__(256) void prep_weights(const float* __restrict__ W_node,
                                                    const float* __restrict__ W_gat,
                                                    ushort* __restrict__ WT) {
    int b = blockIdx.x;
    const float* W = (b == 0) ? W_node : (W_gat + (size_t)(b - 1) * 16384);
    ushort* D = WT + (size_t)b * 16384;
    int t = threadIdx.x;
    int n = t >> 1;
    int k0 = (t & 1) * 64;
    for (int kk = 0; kk < 64; kk++) {
        int k = k0 + kk;
        float v = W[k * 128 + n];
        int u = (k >> 3) ^ (n & 7);
        D[n * 128 + u * 8 + (k & 7)] = f2bf(v);
    }
}

// ---------------- MFMA GEMM: out[N,128] = A_bf16[N,128] @ W (WT staged in LDS)
// MODE 0: write xh bf16 only. MODE 1: +b_node+temb epilogue, write h fp32 + h bf16.
template <int MODE>
__global__ __launch_bounds__(256) void gemm_mfma(
    const ushort* __restrict__ Abf, const ushort* __restrict__ WT,
    ushort* __restrict__ out_bf, float* __restrict__ out_f32,
    const float* __restrict__ bias, const int* __restrict__ ntypes,
    const float* __restrict__ temb, int nrows) {
    __shared__ ushort wlds[16384];  // 32 KB: W^T [n=128][k=128] bf16, swizzled units
    int tid = threadIdx.x;
    int lane = tid & 63;
    int wid = tid >> 6;

    // stage W^T (linear copy; data already swizzled in global)
    {
        const short8* src = (const short8*)WT;
        short8* dst = (short8*)wlds;
#pragma unroll
        for (int i = 0; i < 8; i++) dst[i * 256 + tid] = src[i * 256 + tid];
    }

    // A fragments (global, per-lane): row = rbase + (lane&15), k = ks*32 + (lane>>4)*8
    int rbase = blockIdx.x * 64 + wid * 16;
    int arow = rbase + (lane & 15);
    if (arow >= nrows) arow = nrows - 1;
    const short8* arow_p = (const short8*)(Abf + (size_t)arow * 128);
    short8 afr[4];
#pragma unroll
    for (int ks = 0; ks < 4; ks++) afr[ks] = arow_p[ks * 4 + (lane >> 4)];

    __syncthreads();

    f32x4 acc[8];
#pragma unroll
    for (int i = 0; i < 8; i++) acc[i] = (f32x4){0.f, 0.f, 0.f, 0.f};

    int cgrp = lane & 15;
    int kgrp = lane >> 4;
#pragma unroll
    for (int ks = 0; ks < 4; ks++) {
        short8 a = afr[ks];
#pragma unroll
        for (int nt = 0; nt < 8; nt++) {
            int n = nt * 16 + cgrp;
            int u = (ks * 4 + kgrp) ^ (n & 7);
            short8 b = *(const short8*)&wlds[n * 128 + u * 8];
            acc[nt] = __builtin_amdgcn_mfma_f32_16x16x32_bf16(a, b, acc[nt], 0, 0, 0);
        }
    }

    // epilogue: D col = lane&15, row = rbase + (lane>>4)*4 + r
    int nts[4];
    if (MODE == 1) {
#pragma unroll
        for (int r = 0; r < 4; r++) {
            int row = rbase + kgrp * 4 + r;
            nts[r] = (row < nrows) ? ntypes[row] : 0;
        }
    }
#pragma unroll
    for (int nt = 0; nt < 8; nt++) {
        int colc = nt * 16 + cgrp;
#pragma unroll
        for (int r = 0; r < 4; r++) {
            int row = rbase + kgrp * 4 + r;
            if (row < nrows) {
                float v = acc[nt][r];
                if (MODE == 1) {
                    v += bias[colc] + temb[nts[r] * 128 + colc];
                    out_f32[(size_t)row * 128 + colc] = v;
                }
                out_bf[(size_t)row * 128 + colc] = f2bf(v);
            }
        }
    }
}

// ---------------- per-node attention scores s_src/s_dst [N,4]
__global__ __launch_bounds__(256) void attn_scores(
    const ushort* __restrict__ xh, const float* __restrict__ asrc,
    const float* __restrict__ adst, float* __restrict__ s_src,
    float* __restrict__ s_dst, int n) {
    int tid = threadIdx.x;
    int node = blockIdx.x * 2 + (tid >> 7);
    int c = tid & 127;
    if (node >= n) return;
    int h = c >> 5;
    int cc = c & 31;
    float v = bf2f(xh[(size_t)node * 128 + c]);
    float ps = v * asrc[h * 32 + cc];
    float pd = v * adst[h * 32 + cc];
#pragma unroll
    for (int m = 16; m >= 1; m >>= 1) {
        ps += __shfl_xor(ps, m, 64);
        pd += __shfl_xor(pd, m, 64);
    }
    if (cc == 0) {
        s_src[node * 4 + h] = ps;
        s_dst[node * 4 + h] = pd;
    }
}

// ---------------- CSR build
__global__ void count_edges(const int* __restrict__ dst, int* __restrict__ deg, int ne) {
    int i = blockIdx.x * blockDim.x + threadIdx.x;
    if (i < ne) atomicAdd(&deg[dst[i]], 1);
}

__global__ __launch_bounds__(1024) void scan_kernel(const int* __restrict__ cnt,
                                                    int* __restrict__ row_ptr, int n) {
    __shared__ int partial[1024];
    int tid = threadIdx.x;
    int chunk = (n + 1023) / 1024;
    int start = tid * chunk;
    int end = start + chunk;
    if (end > n) end = n;
    int s = 0;
    for (int i = start; i < end; i++) s += cnt[i];
    partial[tid] = s;
    __syncthreads();
    for (int off = 1; off < 1024; off <<= 1) {
        int v = (tid >= off) ? partial[tid - off] : 0;
        __syncthreads();
        partial[tid] += v;
        __syncthreads();
    }
    int excl = (tid == 0) ? 0 : partial[tid - 1];
    for (int i = start; i < end; i++) {
        row_ptr[i] = excl;
        excl += cnt[i];
    }
    if (tid == 1023) row_ptr[n] = partial[1023];
}

__global__ void fill_edges(const int* __restrict__ ei, const int* __restrict__ row_ptr,
                           int* __restrict__ fill, int* __restrict__ col, int ne) {
    int i = blockIdx.x * blockDim.x + threadIdx.x;
    if (i < ne) {
        int d = ei[ne + i];
        int pos = row_ptr[d] + atomicAdd(&fill[d], 1);
        col[pos] = ei[i];
    }
}

// ---------------- fused GAT aggregate + bias + layernorm + residual relu
// wave per node; online softmax (single edge pass for max+sum), then 4-edge-parallel
// message pass; writes h fp32 and h bf16.
__global__ __launch_bounds__(256) void gat_aggregate(
    const ushort* __restrict__ xh, const float* __restrict__ ssrc,
    const float* __restrict__ sdst, const int* __restrict__ row_ptr,
    const int* __restrict__ col, const float* __restrict__ bg,
    const float* __restrict__ lng, const float* __restrict__ lnb,
    float* __restrict__ h, ushort* __restrict__ hb, int n) {
    int wid = threadIdx.x >> 6;
    int lane = threadIdx.x & 63;
    int node = blockIdx.x * 4 + wid;
    if (node >= n) return;

    int base = row_ptr[node];
    int deg = row_ptr[node + 1] - base;

    float4 sd = ((const float4*)sdst)[node];
    float4 ssf = ((const float4*)ssrc)[node];
    float es0 = lrelu(ssf.x + sd.x), es1 = lrelu(ssf.y + sd.y);
    float es2 = lrelu(ssf.z + sd.z), es3 = lrelu(ssf.w + sd.w);

    // online softmax stats (self-loop seeded in lane 0)
    float m0, m1, m2, m3, z0, z1, z2, z3;
    if (lane == 0) {
        m0 = es0; m1 = es1; m2 = es2; m3 = es3;
        z0 = z1 = z2 = z3 = 1.f;
    } else {
        m0 = m1 = m2 = m3 = -1e30f;
        z0 = z1 = z2 = z3 = 0.f;
    }
    for (int j = lane; j < deg; j += 64) {
        int s = col[base + j];
        float4 ss = ((const float4*)ssrc)[s];
        float e, nm;
        e = lrelu(ss.x + sd.x); nm = fmaxf(m0, e); z0 = z0 * expf(m0 - nm) + expf(e - nm); m0 = nm;
        e = lrelu(ss.y + sd.y); nm = fmaxf(m1, e); z1 = z1 * expf(m1 - nm) + expf(e - nm); m1 = nm;
        e = lrelu(ss.z + sd.z); nm = fmaxf(m2, e); z2 = z2 * expf(m2 - nm) + expf(e - nm); m2 = nm;
        e = lrelu(ss.w + sd.w); nm = fmaxf(m3, e); z3 = z3 * expf(m3 - nm) + expf(e - nm); m3 = nm;
    }
#pragma unroll
    for (int off = 32; off >= 1; off >>= 1) {
        float om, oz, nm;
        om = __shfl_xor(m0, off, 64); oz = __shfl_xor(z0, off, 64);
        nm = fmaxf(m0, om); z0 = z0 * expf(m0 - nm) + oz * expf(om - nm); m0 = nm;
        om = __shfl_xor(m1, off, 64); oz = __shfl_xor(z1, off, 64);
        nm = fmaxf(m1, om); z1 = z1 * expf(m1 - nm) + oz * expf(om - nm); m1 = nm;
        om = __shfl_xor(m2, off, 64); oz = __shfl_xor(z2, off, 64);
        nm = fmaxf(m2, om); z2 = z2 * expf(m2 - nm) + oz * expf(om - nm); m2 = nm;
        om = __shfl_xor(m3, off, 64); oz = __shfl_xor(z3, off, 64);
        nm = fmaxf(m3, om); z3 = z3 * expf(m3 - nm) + oz * expf(om - nm); m3 = nm;
    }
    float i0 = 1.f / (z0 + 1e-16f), i1 = 1.f / (z1 + 1e-16f);
    float i2 = 1.f / (z2 + 1e-16f), i3 = 1.f / (z3 + 1e-16f);

    // message pass: eg = edge group (0..3), g = channel group (8 ch), head = g>>2
    int eg = lane >> 4;
    int g = lane & 15;
    int head = g >> 2;
    float sdH = pick4(head, sd.x, sd.y, sd.z, sd.w);
    float mH = pick4(head, m0, m1, m2, m3);
    float iH = pick4(head, i0, i1, i2, i3);
    float esH = pick4(head, es0, es1, es2, es3);

    float acc[8];
#pragma unroll
    for (int k = 0; k < 8; k++) acc[k] = 0.f;

    if (eg == 0) {
        float aS = expf(esH - mH) * iH;
        short8 xv = *(const short8*)(xh + (size_t)node * 128 + g * 8);
#pragma unroll
        for (int k = 0; k < 8; k++) acc[k] += aS * bf2f((ushort)xv[k]);
    }

    int nit = (deg + 3) >> 2;
    for (int t = 0; t < nit; t++) {
        int j = t * 4 + eg;
        if (j < deg) {
            int s = col[base + j];
            float4 ss = ((const float4*)ssrc)[s];
            float sH = pick4(head, ss.x, ss.y, ss.z, ss.w);
            float a = expf(lrelu(sH + sdH) - mH) * iH;
            short8 xv = *(const short8*)(xh + (size_t)s * 128 + g * 8);
#pragma unroll
            for (int k = 0; k < 8; k++) acc[k] += a * bf2f((ushort)xv[k]);
        }
    }
#pragma unroll
    for (int k = 0; k < 8; k++) {
        acc[k] += __shfl_xor(acc[k], 16, 64);
        acc[k] += __shfl_xor(acc[k], 32, 64);
    }

    // bias + layernorm (channels replicated 4x across wave -> /512)
    const float4* bg4 = (const float4*)(bg + g * 8);
    float4 b0 = bg4[0], b1 = bg4[1];
    float o[8];
    o[0] = acc[0] + b0.x; o[1] = acc[1] + b0.y; o[2] = acc[2] + b0.z; o[3] = acc[3] + b0.w;
    o[4] = acc[4] + b1.x; o[5] = acc[5] + b1.y; o[6] = acc[6] + b1.z; o[7] = acc[7] + b1.w;

    float ls = 0.f;
#pragma unroll
    for (int k = 0; k < 8; k++) ls += o[k];
    float mu = wred_sum(ls) * (1.f / 512.f);
    float vs = 0.f;
#pragma unroll
    for (int k = 0; k < 8; k++) {
        o[k] -= mu;
        vs += o[k] * o[k];
    }
    float var = wred_sum(vs) * (1.f / 512.f);
    float rs = rsqrtf(var + 1e-5f);

    if (eg == 0) {
        const float4* lg4 = (const float4*)(lng + g * 8);
        const float4* lb4 = (const float4*)(lnb + g * 8);
        float4 g0 = lg4[0], g1 = lg4[1];
        float4 q0 = lb4[0], q1 = lb4[1];
        float* hr = h + (size_t)node * 128 + g * 8;
        float4* hr4 = (float4*)hr;
        float4 p0 = hr4[0], p1 = hr4[1];
        float y[8];
        y[0] = fmaxf(o[0] * rs * g0.x + q0.x + p0.x, 0.f);
        y[1] = fmaxf(o[1] * rs * g0.y + q0.y + p0.y, 0.f);
        y[2] = fmaxf(o[2] * rs * g0.z + q0.z + p0.z, 0.f);
        y[3] = fmaxf(o[3] * rs * g0.w + q0.w + p0.w, 0.f);
        y[4] = fmaxf(o[4] * rs * g1.x + q1.x + p1.x, 0.f);
        y[5] = fmaxf(o[5] * rs * g1.y + q1.y + p1.y, 0.f);
        y[6] = fmaxf(o[6] * rs * g1.z + q1.z + p1.z, 0.f);
        y[7] = fmaxf(o[7] * rs * g1.w + q1.w + p1.w, 0.f);
        float4 w0 = make_float4(y[0], y[1], y[2], y[3]);
        float4 w1 = make_float4(y[4], y[5], y[6], y[7]);
        hr4[0] = w0;
        hr4[1] = w1;
        short8 ob;
#pragma unroll
        for (int k = 0; k < 8; k++) ob[k] = (short)f2bf(y[k]);
        *(short8*)(hb + (size_t)node * 128 + g * 8) = ob;
    }
}

// ---------------- mean pool (batch sorted -> run-length atomics)
__global__ __launch_bounds__(256) void pool_kernel(const float* __restrict__ h,
                                                   const int* __restrict__ batch,
                                                   float* __restrict__ sums,
                                                   int* __restrict__ cnts, int n) {
    int c = threadIdx.x & 127;
    int half = threadIdx.x >> 7;
    int n0 = blockIdx.x * 64;
    float acc = 0.f;
    int cur = -1;
    for (int idx = half; idx < 64; idx += 2) {
        int node = n0 + idx;
        if (node >= n) break;
        int g = batch[node];
        if (g != cur) {
            if (cur >= 0) atomicAdd(&sums[cur * 128 + c], acc);
            cur = g;
            acc = 0.f;
        }
        acc += h[(size_t)node * 128 + c];
    }
    if (cur >= 0) atomicAdd(&sums[cur * 128 + c], acc);

    if (c == 0) {
        int cnt = 0, curg = -1;
        for (int idx = half; idx < 64; idx += 2) {
            int node = n0 + idx;
            if (node >= n) break;
            int g = batch[node];
            if (g != curg) {
                if (curg >= 0) atomicAdd(&cnts[curg], cnt);
                curg = g;
                cnt = 0;
            }
            cnt++;
        }
        if (curg >= 0) atomicAdd(&cnts[curg], cnt);
    }
}

// ---------------- MLP head: one block per graph
__global__ __launch_bounds__(256) void head_kernel(
    const float* __restrict__ sums, const int* __restrict__ cnts,
    const float* __restrict__ W1, const float* __restrict__ b1,
    const float* __restrict__ W2, const float* __restrict__ b2,
    const float* __restrict__ W3, const float* __restrict__ b3,
    float* __restrict__ out) {
    __shared__ float hg[128], z1[256], z2[128];
    int g = blockIdx.x;
    int t = threadIdx.x;
    if (t < 128) hg[t] = sums[g * 128 + t] / fmaxf((float)cnts[g], 1.f);
    __syncthreads();
    {
        float acc = b1[t];
        for (int k = 0; k < 128; k++) acc += hg[k] * W1[k * 256 + t];
        z1[t] = fmaxf(acc, 0.f);
    }
    __syncthreads();
    if (t < 128) {
        float acc = b2[t];
        for (int k = 0; k < 256; k++) acc += z1[k] * W2[k * 128 + t];
        z2[t] = fmaxf(acc, 0.f);
    }
    __syncthreads();
    if (t < NCLS) {
        float acc = b3[t];
        for (int k = 0; k < 128; k++) acc += z2[k] * W3[k * NCLS + t];
        out[g * NCLS + t] = acc;
    }
}

extern "C" void kernel_launch(void* const* d_in, const int* in_sizes, int n_in,
                              void* d_out, int out_size, void* d_ws, size_t ws_size,
                              hipStream_t stream) {
    const float* x = (const float*)d_in[0];
    const int* ei = (const int*)d_in[1];
    const int* ntypes = (const int*)d_in[2];
    const int* batch = (const int*)d_in[3];
    const float* W_node = (const float*)d_in[4];
    const float* b_node = (const float*)d_in[5];
    const float* temb = (const float*)d_in[6];
    const float* W_gat = (const float*)d_in[7];
    const float* a_src = (const float*)d_in[8];
    const float* a_dst = (const float*)d_in[9];
    const float* b_gat = (const float*)d_in[10];
    const float* ln_g = (const float*)d_in[11];
    const float* ln_b = (const float*)d_in[12];
    const float* W1 = (const float*)d_in[13];
    const float* b1 = (const float*)d_in[14];
    const float* W2 = (const float*)d_in[15];
    const float* b2 = (const float*)d_in[16];
    const float* W3 = (const float*)d_in[17];
    const float* b3 = (const float*)d_in[18];
    float* out = (float*)d_out;

    char* ws = (char*)d_ws;
    size_t off = 0;
    auto alloc = [&](size_t bytes) {
        void* p = ws + off;
        off += (bytes + 255) & ~(size_t)255;
        return p;
    };
    float* h = (float*)alloc((size_t)NN * 128 * 4);      // fp32 h (residual/pool)
    ushort* hb = (ushort*)alloc((size_t)NN * 128 * 2);   // bf16 h (GEMM input)
    ushort* xhb = (ushort*)alloc((size_t)NN * 128 * 2);  // bf16 xh; aliases x_bf16
    ushort* WT = (ushort*)alloc((size_t)4 * 16384 * 2);  // 4x W^T bf16 swizzled
    float* ssrc = (float*)alloc((size_t)NN * 4 * 4);
    float* sdst = (float*)alloc((size_t)NN * 4 * 4);
    int* rowp = (int*)alloc((size_t)(NN + 1) * 4);
    int* fillc = (int*)alloc((size_t)NN * 4);
    int* col = (int*)alloc((size_t)EE * 4);
    float* psum = (float*)alloc((size_t)NGRAPH * 128 * 4);
    int* pcnt = (int*)alloc((size_t)NGRAPH * 4);

    hipError_t e0;
    e0 = hipMemsetAsync(fillc, 0, (size_t)NN * 4, stream); (void)e0;
    e0 = hipMemsetAsync(psum, 0, (size_t)NGRAPH * 128 * 4, stream); (void)e0;
    e0 = hipMemsetAsync(pcnt, 0, (size_t)NGRAPH * 4, stream); (void)e0;

    // prep: x -> bf16 (into xhb), weights -> W^T bf16 swizzled
    convert_x<<<3125, 256, 0, stream>>>(x, xhb);
    prep_weights<<<4, 256, 0, stream>>>(W_node, W_gat, WT);

    // CSR build
    count_edges<<<(EE + 255) / 256, 256, 0, stream>>>(ei + EE, fillc, EE);
    scan_kernel<<<1, 1024, 0, stream>>>(fillc, rowp, NN);
    e0 = hipMemsetAsync(fillc, 0, (size_t)NN * 4, stream); (void)e0;
    fill_edges<<<(EE + 255) / 256, 256, 0, stream>>>(ei, rowp, fillc, col, EE);

    // node init: h = x@W_node + b_node + temb[ntypes]  (fp32 + bf16)
    int gemm_grid = (NN + 63) / 64;
    gemm_mfma<1><<<gemm_grid, 256, 0, stream>>>(xhb, WT, hb, h, b_node, ntypes, temb, NN);

    for (int l = 0; l < LL; l++) {
        gemm_mfma<0><<<gemm_grid, 256, 0, stream>>>(hb, WT + (size_t)(l + 1) * 16384, xhb,
                                                    nullptr, nullptr, nullptr, nullptr, NN);
        attn_scores<<<(NN + 1) / 2, 256, 0, stream>>>(xhb, a_src + l * HEADS * CC,
                                                      a_dst + l * HEADS * CC, ssrc, sdst, NN);
        gat_aggregate<<<(NN + 3) / 4, 256, 0, stream>>>(
            xhb, ssrc, sdst, rowp, col, b_gat + l * 128, ln_g + l * 128, ln_b + l * 128,
            h, hb, NN);
    }

    pool_kernel<<<(NN + 63) / 64, 256, 0, stream>>>(h, batch, psum, pcnt, NN);
    head_kernel<<<NGRAPH, 256, 0, stream>>>(psum, pcnt, W1, b1, W2, b2, W3, b3, out);
}

// Round 5
// 504.455 us; speedup vs baseline: 2.3448x; 1.1814x over previous
//
#include <hip/hip_runtime.h>
#include <hip/hip_bf16.h>

#define NN 50000
#define EE 800000
#define IN_DIM 128
#define HH 128
#define HEADS 4
#define CC 32
#define LL 3
#define NCLS 10
#define NGRAPH 64

using short8 = __attribute__((ext_vector_type(8))) short;
using f32x4 = __attribute__((ext_vector_type(4))) float;

__device__ inline float lrelu(float x) { return fmaxf(x, 0.2f * x); }
__device__ inline float fexp(float x) { return __expf(x); }

__device__ inline float bf2f(ushort u) {
    union { uint32_t i; float f; } c;
    c.i = ((uint32_t)u) << 16;
    return c.f;
}
__device__ inline ushort f2bf(float f) {
    union { float f; uint32_t i; } c;
    c.f = f;
    uint32_t x = c.i;
    uint32_t r = (x + 0x7fffu + ((x >> 16) & 1u)) >> 16;
    return (ushort)r;
}

__device__ inline float wred_sum(float v) {
#pragma unroll
    for (int m = 32; m >= 1; m >>= 1) v += __shfl_xor(v, m, 64);
    return v;
}

__device__ inline float pick4(int h, float a, float b, float c, float d) {
    float ab = (h & 1) ? b : a;
    float cd = (h & 1) ? d : c;
    return (h & 2) ? cd : ab;
}

// ---------------- x -> bf16 (6.4M elements, 8/thread)
__global__ __launch_bounds__(256) void convert_x(const float* __restrict__ x,
                                                 ushort* __restrict__ xb) {
    int u = blockIdx.x * 256 + threadIdx.x;  // ushort8 unit
    const float4* x4 = (const float4*)x;
    float4 f0 = x4[u * 2];
    float4 f1 = x4[u * 2 + 1];
    short8 o;
    o[0] = (short)f2bf(f0.x); o[1] = (short)f2bf(f0.y);
    o[2] = (short)f2bf(f0.z); o[3] = (short)f2bf(f0.w);
    o[4] = (short)f2bf(f1.x); o[5] = (short)f2bf(f1.y);
    o[6] = (short)f2bf(f1.z); o[7] = (short)f2bf(f1.w);
    ((short8*)xb)[u] = o;
}

// ---------------- weights -> W^T bf16, pre-swizzled (16B unit u ^= n&7)
// block b: 0 = W_node, 1..3 = W_gat[l]
__global__ __launch_bounds__(256) void prep_weights(const float* __restrict__ W_node,
                                                    const float* __restrict__ W_gat,
                                                    ushort* __restrict__ WT) {
    int b = blockIdx.x;
    const float* W = (b == 0) ? W_node : (W_gat + (size_t)(b - 1) * 16384);
    ushort* D = WT + (size_t)b * 16384;
    int t = threadIdx.x;
    int n = t >> 1;
    int k0 = (t & 1) * 64;
    for (int kk = 0; kk < 64; kk++) {
        int k = k0 + kk;
        float v = W[k * 128 + n];
        int u = (k >> 3) ^ (n & 7);
        D[n * 128 + u * 8 + (k & 7)] = f2bf(v);
    }
}

// ---------------- MFMA GEMM: out[N,128] = A_bf16[N,128] @ W (WT staged in LDS)
// MODE 0: write xh bf16 only. MODE 1: +b_node+temb epilogue, write h fp32 + h bf16.
template <int MODE>
__global__ __launch_bounds__(256) void gemm_mfma(
    const ushort* __restrict__ Abf, const ushort* __restrict__ WT,
    ushort* __restrict__ out_bf, float* __restrict__ out_f32,
    const float* __restrict__ bias, const int* __restrict__ ntypes,
    const float* __restrict__ temb, int nrows) {
    __shared__ ushort wlds[16384];  // 32 KB: W^T [n=128][k=128] bf16, swizzled units
    int tid = threadIdx.x;
    int lane = tid & 63;
    int wid = tid >> 6;

    // stage W^T (linear copy; data already swizzled in global)
    {
        const short8* src = (const short8*)WT;
        short8* dst = (short8*)wlds;
#pragma unroll
        for (int i = 0; i < 8; i++) dst[i * 256 + tid] = src[i * 256 + tid];
    }

    // A fragments (global, per-lane): row = rbase + (lane&15), k = ks*32 + (lane>>4)*8
    int rbase = blockIdx.x * 64 + wid * 16;
    int arow = rbase + (lane & 15);
    if (arow >= nrows) arow = nrows - 1;
    const short8* arow_p = (const short8*)(Abf + (size_t)arow * 128);
    short8 afr[4];
#pragma unroll
    for (int ks = 0; ks < 4; ks++) afr[ks] = arow_p[ks * 4 + (lane >> 4)];

    __syncthreads();

    f32x4 acc[8];
#pragma unroll
    for (int i = 0; i < 8; i++) acc[i] = (f32x4){0.f, 0.f, 0.f, 0.f};

    int cgrp = lane & 15;
    int kgrp = lane >> 4;
#pragma unroll
    for (int ks = 0; ks < 4; ks++) {
        short8 a = afr[ks];
#pragma unroll
        for (int nt = 0; nt < 8; nt++) {
            int n = nt * 16 + cgrp;
            int u = (ks * 4 + kgrp) ^ (n & 7);
            short8 b = *(const short8*)&wlds[n * 128 + u * 8];
            acc[nt] = __builtin_amdgcn_mfma_f32_16x16x32_bf16(a, b, acc[nt], 0, 0, 0);
        }
    }

    // epilogue: D col = lane&15, row = rbase + (lane>>4)*4 + r
    int nts[4];
    if (MODE == 1) {
#pragma unroll
        for (int r = 0; r < 4; r++) {
            int row = rbase + kgrp * 4 + r;
            nts[r] = (row < nrows) ? ntypes[row] : 0;
        }
    }
#pragma unroll
    for (int nt = 0; nt < 8; nt++) {
        int colc = nt * 16 + cgrp;
#pragma unroll
        for (int r = 0; r < 4; r++) {
            int row = rbase + kgrp * 4 + r;
            if (row < nrows) {
                float v = acc[nt][r];
                if (MODE == 1) {
                    v += bias[colc] + temb[nts[r] * 128 + colc];
                    out_f32[(size_t)row * 128 + colc] = v;
                }
                out_bf[(size_t)row * 128 + colc] = f2bf(v);
            }
        }
    }
}

// ---------------- per-node attention scores s_src/s_dst [N,4]
__global__ __launch_bounds__(256) void attn_scores(
    const ushort* __restrict__ xh, const float* __restrict__ asrc,
    const float* __restrict__ adst, float* __restrict__ s_src,
    float* __restrict__ s_dst, int n) {
    int tid = threadIdx.x;
    int node = blockIdx.x * 2 + (tid >> 7);
    int c = tid & 127;
    if (node >= n) return;
    int h = c >> 5;
    int cc = c & 31;
    float v = bf2f(xh[(size_t)node * 128 + c]);
    float ps = v * asrc[h * 32 + cc];
    float pd = v * adst[h * 32 + cc];
#pragma unroll
    for (int m = 16; m >= 1; m >>= 1) {
        ps += __shfl_xor(ps, m, 64);
        pd += __shfl_xor(pd, m, 64);
    }
    if (cc == 0) {
        s_src[node * 4 + h] = ps;
        s_dst[node * 4 + h] = pd;
    }
}

// ---------------- CSR build
__global__ void count_edges(const int* __restrict__ dst, int* __restrict__ deg, int ne) {
    int i = blockIdx.x * blockDim.x + threadIdx.x;
    if (i < ne) atomicAdd(&deg[dst[i]], 1);
}

__global__ __launch_bounds__(1024) void scan_kernel(const int* __restrict__ cnt,
                                                    int* __restrict__ row_ptr, int n) {
    __shared__ int partial[1024];
    int tid = threadIdx.x;
    int chunk = (n + 1023) / 1024;
    int start = tid * chunk;
    int end = start + chunk;
    if (end > n) end = n;
    int s = 0;
    for (int i = start; i < end; i++) s += cnt[i];
    partial[tid] = s;
    __syncthreads();
    for (int off = 1; off < 1024; off <<= 1) {
        int v = (tid >= off) ? partial[tid - off] : 0;
        __syncthreads();
        partial[tid] += v;
        __syncthreads();
    }
    int excl = (tid == 0) ? 0 : partial[tid - 1];
    for (int i = start; i < end; i++) {
        row_ptr[i] = excl;
        excl += cnt[i];
    }
    if (tid == 1023) row_ptr[n] = partial[1023];
}

__global__ void fill_edges(const int* __restrict__ ei, const int* __restrict__ row_ptr,
                           int* __restrict__ fill, int* __restrict__ col, int ne) {
    int i = blockIdx.x * blockDim.x + threadIdx.x;
    if (i < ne) {
        int d = ei[ne + i];
        int pos = row_ptr[d] + atomicAdd(&fill[d], 1);
        col[pos] = ei[i];
    }
}

// ---------------- fused GAT aggregate + bias + layernorm + residual relu
// wave per node; per-lane online softmax, cheap cross-lane merge (max-reduce,
// one rescale, sum-reduce), 4-edge-parallel message pass; fast __expf everywhere.
__global__ __launch_bounds__(256) void gat_aggregate(
    const ushort* __restrict__ xh, const float* __restrict__ ssrc,
    const float* __restrict__ sdst, const int* __restrict__ row_ptr,
    const int* __restrict__ col, const float* __restrict__ bg,
    const float* __restrict__ lng, const float* __restrict__ lnb,
    float* __restrict__ h, ushort* __restrict__ hb, int n) {
    int wid = threadIdx.x >> 6;
    int lane = threadIdx.x & 63;
    int node = blockIdx.x * 4 + wid;
    if (node >= n) return;

    int base = row_ptr[node];
    int deg = row_ptr[node + 1] - base;

    float4 sd = ((const float4*)sdst)[node];
    float4 ssf = ((const float4*)ssrc)[node];
    float es0 = lrelu(ssf.x + sd.x), es1 = lrelu(ssf.y + sd.y);
    float es2 = lrelu(ssf.z + sd.z), es3 = lrelu(ssf.w + sd.w);

    // per-lane online softmax stats (self-loop seeded in lane 0)
    float m0, m1, m2, m3, z0, z1, z2, z3;
    if (lane == 0) {
        m0 = es0; m1 = es1; m2 = es2; m3 = es3;
        z0 = z1 = z2 = z3 = 1.f;
    } else {
        m0 = m1 = m2 = m3 = -1e30f;
        z0 = z1 = z2 = z3 = 0.f;
    }
    for (int j = lane; j < deg; j += 64) {
        int s = col[base + j];
        float4 ss = ((const float4*)ssrc)[s];
        float e, nm;
        e = lrelu(ss.x + sd.x); nm = fmaxf(m0, e); z0 = z0 * fexp(m0 - nm) + fexp(e - nm); m0 = nm;
        e = lrelu(ss.y + sd.y); nm = fmaxf(m1, e); z1 = z1 * fexp(m1 - nm) + fexp(e - nm); m1 = nm;
        e = lrelu(ss.z + sd.z); nm = fmaxf(m2, e); z2 = z2 * fexp(m2 - nm) + fexp(e - nm); m2 = nm;
        e = lrelu(ss.w + sd.w); nm = fmaxf(m3, e); z3 = z3 * fexp(m3 - nm) + fexp(e - nm); m3 = nm;
    }
    // cross-lane: max-reduce, one rescale, sum-reduce
    float lm0 = m0, lm1 = m1, lm2 = m2, lm3 = m3;
#pragma unroll
    for (int off = 32; off >= 1; off >>= 1) {
        m0 = fmaxf(m0, __shfl_xor(m0, off, 64));
        m1 = fmaxf(m1, __shfl_xor(m1, off, 64));
        m2 = fmaxf(m2, __shfl_xor(m2, off, 64));
        m3 = fmaxf(m3, __shfl_xor(m3, off, 64));
    }
    z0 *= fexp(lm0 - m0);
    z1 *= fexp(lm1 - m1);
    z2 *= fexp(lm2 - m2);
    z3 *= fexp(lm3 - m3);
#pragma unroll
    for (int off = 32; off >= 1; off >>= 1) {
        z0 += __shfl_xor(z0, off, 64);
        z1 += __shfl_xor(z1, off, 64);
        z2 += __shfl_xor(z2, off, 64);
        z3 += __shfl_xor(z3, off, 64);
    }
    float i0 = 1.f / (z0 + 1e-16f), i1 = 1.f / (z1 + 1e-16f);
    float i2 = 1.f / (z2 + 1e-16f), i3 = 1.f / (z3 + 1e-16f);

    // message pass: eg = edge group (0..3), g = channel group (8 ch), head = g>>2
    int eg = lane >> 4;
    int g = lane & 15;
    int head = g >> 2;
    float sdH = pick4(head, sd.x, sd.y, sd.z, sd.w);
    float mH = pick4(head, m0, m1, m2, m3);
    float iH = pick4(head, i0, i1, i2, i3);
    float esH = pick4(head, es0, es1, es2, es3);

    float acc[8];
#pragma unroll
    for (int k = 0; k < 8; k++) acc[k] = 0.f;

    if (eg == 0) {
        float aS = fexp(esH - mH) * iH;
        short8 xv = *(const short8*)(xh + (size_t)node * 128 + g * 8);
#pragma unroll
        for (int k = 0; k < 8; k++) acc[k] += aS * bf2f((ushort)xv[k]);
    }

    int nit = (deg + 3) >> 2;
#pragma unroll 2
    for (int t = 0; t < nit; t++) {
        int j = t * 4 + eg;
        if (j < deg) {
            int s = col[base + j];
            float4 ss = ((const float4*)ssrc)[s];
            float sH = pick4(head, ss.x, ss.y, ss.z, ss.w);
            float a = fexp(lrelu(sH + sdH) - mH) * iH;
            short8 xv = *(const short8*)(xh + (size_t)s * 128 + g * 8);
#pragma unroll
            for (int k = 0; k < 8; k++) acc[k] += a * bf2f((ushort)xv[k]);
        }
    }
#pragma unroll
    for (int k = 0; k < 8; k++) {
        acc[k] += __shfl_xor(acc[k], 16, 64);
        acc[k] += __shfl_xor(acc[k], 32, 64);
    }

    // bias + layernorm (channels replicated 4x across wave -> /512)
    const float4* bg4 = (const float4*)(bg + g * 8);
    float4 b0 = bg4[0], b1 = bg4[1];
    float o[8];
    o[0] = acc[0] + b0.x; o[1] = acc[1] + b0.y; o[2] = acc[2] + b0.z; o[3] = acc[3] + b0.w;
    o[4] = acc[4] + b1.x; o[5] = acc[5] + b1.y; o[6] = acc[6] + b1.z; o[7] = acc[7] + b1.w;

    float ls = 0.f;
#pragma unroll
    for (int k = 0; k < 8; k++) ls += o[k];
    float mu = wred_sum(ls) * (1.f / 512.f);
    float vs = 0.f;
#pragma unroll
    for (int k = 0; k < 8; k++) {
        o[k] -= mu;
        vs += o[k] * o[k];
    }
    float var = wred_sum(vs) * (1.f / 512.f);
    float rs = rsqrtf(var + 1e-5f);

    if (eg == 0) {
        const float4* lg4 = (const float4*)(lng + g * 8);
        const float4* lb4 = (const float4*)(lnb + g * 8);
        float4 g0 = lg4[0], g1 = lg4[1];
        float4 q0 = lb4[0], q1 = lb4[1];
        float* hr = h + (size_t)node * 128 + g * 8;
        float4* hr4 = (float4*)hr;
        float4 p0 = hr4[0], p1 = hr4[1];
        float y[8];
        y[0] = fmaxf(o[0] * rs * g0.x + q0.x + p0.x, 0.f);
        y[1] = fmaxf(o[1] * rs * g0.y + q0.y + p0.y, 0.f);
        y[2] = fmaxf(o[2] * rs * g0.z + q0.z + p0.z, 0.f);
        y[3] = fmaxf(o[3] * rs * g0.w + q0.w + p0.w, 0.f);
        y[4] = fmaxf(o[4] * rs * g1.x + q1.x + p1.x, 0.f);
        y[5] = fmaxf(o[5] * rs * g1.y + q1.y + p1.y, 0.f);
        y[6] = fmaxf(o[6] * rs * g1.z + q1.z + p1.z, 0.f);
        y[7] = fmaxf(o[7] * rs * g1.w + q1.w + p1.w, 0.f);
        float4 w0 = make_float4(y[0], y[1], y[2], y[3]);
        float4 w1 = make_float4(y[4], y[5], y[6], y[7]);
        hr4[0] = w0;
        hr4[1] = w1;
        short8 ob;
#pragma unroll
        for (int k = 0; k < 8; k++) ob[k] = (short)f2bf(y[k]);
        *(short8*)(hb + (size_t)node * 128 + g * 8) = ob;
    }
}

// ---------------- mean pool (batch sorted -> run-length atomics)
__global__ __launch_bounds__(256) void pool_kernel(const float* __restrict__ h,
                                                   const int* __restrict__ batch,
                                                   float* __restrict__ sums,
                                                   int* __restrict__ cnts, int n) {
    int c = threadIdx.x & 127;
    int half = threadIdx.x >> 7;
    int n0 = blockIdx.x * 64;
    float acc = 0.f;
    int cur = -1;
    for (int idx = half; idx < 64; idx += 2) {
        int node = n0 + idx;
        if (node >= n) break;
        int g = batch[node];
        if (g != cur) {
            if (cur >= 0) atomicAdd(&sums[cur * 128 + c], acc);
            cur = g;
            acc = 0.f;
        }
        acc += h[(size_t)node * 128 + c];
    }
    if (cur >= 0) atomicAdd(&sums[cur * 128 + c], acc);

    if (c == 0) {
        int cnt = 0, curg = -1;
        for (int idx = half; idx < 64; idx += 2) {
            int node = n0 + idx;
            if (node >= n) break;
            int g = batch[node];
            if (g != curg) {
                if (curg >= 0) atomicAdd(&cnts[curg], cnt);
                curg = g;
                cnt = 0;
            }
            cnt++;
        }
        if (curg >= 0) atomicAdd(&cnts[curg], cnt);
    }
}

// ---------------- MLP head: one block per graph
__global__ __launch_bounds__(256) void head_kernel(
    const float* __restrict__ sums, const int* __restrict__ cnts,
    const float* __restrict__ W1, const float* __restrict__ b1,
    const float* __restrict__ W2, const float* __restrict__ b2,
    const float* __restrict__ W3, const float* __restrict__ b3,
    float* __restrict__ out) {
    __shared__ float hg[128], z1[256], z2[128];
    int g = blockIdx.x;
    int t = threadIdx.x;
    if (t < 128) hg[t] = sums[g * 128 + t] / fmaxf((float)cnts[g], 1.f);
    __syncthreads();
    {
        float acc = b1[t];
        for (int k = 0; k < 128; k++) acc += hg[k] * W1[k * 256 + t];
        z1[t] = fmaxf(acc, 0.f);
    }
    __syncthreads();
    if (t < 128) {
        float acc = b2[t];
        for (int k = 0; k < 256; k++) acc += z1[k] * W2[k * 128 + t];
        z2[t] = fmaxf(acc, 0.f);
    }
    __syncthreads();
    if (t < NCLS) {
        float acc = b3[t];
        for (int k = 0; k < 128; k++) acc += z2[k] * W3[k * NCLS + t];
        out[g * NCLS + t] = acc;
    }
}

extern "C" void kernel_launch(void* const* d_in, const int* in_sizes, int n_in,
                              void* d_out, int out_size, void* d_ws, size_t ws_size,
                              hipStream_t stream) {
    const float* x = (const float*)d_in[0];
    const int* ei = (const int*)d_in[1];
    const int* ntypes = (const int*)d_in[2];
    const int* batch = (const int*)d_in[3];
    const float* W_node = (const float*)d_in[4];
    const float* b_node = (const float*)d_in[5];
    const float* temb = (const float*)d_in[6];
    const float* W_gat = (const float*)d_in[7];
    const float* a_src = (const float*)d_in[8];
    const float* a_dst = (const float*)d_in[9];
    const float* b_gat = (const float*)d_in[10];
    const float* ln_g = (const float*)d_in[11];
    const float* ln_b = (const float*)d_in[12];
    const float* W1 = (const float*)d_in[13];
    const float* b1 = (const float*)d_in[14];
    const float* W2 = (const float*)d_in[15];
    const float* b2 = (const float*)d_in[16];
    const float* W3 = (const float*)d_in[17];
    const float* b3 = (const float*)d_in[18];
    float* out = (float*)d_out;

    char* ws = (char*)d_ws;
    size_t off = 0;
    auto alloc = [&](size_t bytes) {
        void* p = ws + off;
        off += (bytes + 255) & ~(size_t)255;
        return p;
    };
    float* h = (float*)alloc((size_t)NN * 128 * 4);      // fp32 h (residual/pool)
    ushort* hb = (ushort*)alloc((size_t)NN * 128 * 2);   // bf16 h (GEMM input)
    ushort* xhb = (ushort*)alloc((size_t)NN * 128 * 2);  // bf16 xh; aliases x_bf16
    ushort* WT = (ushort*)alloc((size_t)4 * 16384 * 2);  // 4x W^T bf16 swizzled
    float* ssrc = (float*)alloc((size_t)NN * 4 * 4);
    float* sdst = (float*)alloc((size_t)NN * 4 * 4);
    int* rowp = (int*)alloc((size_t)(NN + 1) * 4);
    int* fillc = (int*)alloc((size_t)NN * 4);
    int* col = (int*)alloc((size_t)EE * 4);
    float* psum = (float*)alloc((size_t)NGRAPH * 128 * 4);
    int* pcnt = (int*)alloc((size_t)NGRAPH * 4);

    hipError_t e0;
    e0 = hipMemsetAsync(fillc, 0, (size_t)NN * 4, stream); (void)e0;
    e0 = hipMemsetAsync(psum, 0, (size_t)NGRAPH * 128 * 4, stream); (void)e0;
    e0 = hipMemsetAsync(pcnt, 0, (size_t)NGRAPH * 4, stream); (void)e0;

    // prep: x -> bf16 (into xhb), weights -> W^T bf16 swizzled
    convert_x<<<3125, 256, 0, stream>>>(x, xhb);
    prep_weights<<<4, 256, 0, stream>>>(W_node, W_gat, WT);

    // CSR build
    count_edges<<<(EE + 255) / 256, 256, 0, stream>>>(ei + EE, fillc, EE);
    scan_kernel<<<1, 1024, 0, stream>>>(fillc, rowp, NN);
    e0 = hipMemsetAsync(fillc, 0, (size_t)NN * 4, stream); (void)e0;
    fill_edges<<<(EE + 255) / 256, 256, 0, stream>>>(ei, rowp, fillc, col, EE);

    // node init: h = x@W_node + b_node + temb[ntypes]  (fp32 + bf16)
    int gemm_grid = (NN + 63) / 64;
    gemm_mfma<1><<<gemm_grid, 256, 0, stream>>>(xhb, WT, hb, h, b_node, ntypes, temb, NN);

    for (int l = 0; l < LL; l++) {
        gemm_mfma<0><<<gemm_grid, 256, 0, stream>>>(hb, WT + (size_t)(l + 1) * 16384, xhb,
                                                    nullptr, nullptr, nullptr, nullptr, NN);
        attn_scores<<<(NN + 1) / 2, 256, 0, stream>>>(xhb, a_src + l * HEADS * CC,
                                                      a_dst + l * HEADS * CC, ssrc, sdst, NN);
        gat_aggregate<<<(NN + 3) / 4, 256, 0, stream>>>(
            xhb, ssrc, sdst, rowp, col, b_gat + l * 128, ln_g + l * 128, ln_b + l * 128,
            h, hb, NN);
    }

    pool_kernel<<<(NN + 63) / 64, 256, 0, stream>>>(h, batch, psum, pcnt, NN);
    head_kernel<<<NGRAPH, 256, 0, stream>>>(psum, pcnt, W1, b1, W2, b2, W3, b3, out);
}

// Round 6
// 399.297 us; speedup vs baseline: 2.9624x; 1.2634x over previous
//
#include <hip/hip_runtime.h>
#include <hip/hip_bf16.h>

#define NN 50000
#define EE 800000
#define IN_DIM 128
#define HH 128
#define HEADS 4
#define CC 32
#define LL 3
#define NCLS 10
#define NGRAPH 64
#define SNB ((NN + 1023) / 1024)  // 49 scan blocks

using short8 = __attribute__((ext_vector_type(8))) short;
using f32x4 = __attribute__((ext_vector_type(4))) float;

__device__ inline float lrelu(float x) { return fmaxf(x, 0.2f * x); }
__device__ inline float fexp(float x) { return __expf(x); }

__device__ inline float bf2f(ushort u) {
    union { uint32_t i; float f; } c;
    c.i = ((uint32_t)u) << 16;
    return c.f;
}
__device__ inline ushort f2bf(float f) {
    union { float f; uint32_t i; } c;
    c.f = f;
    uint32_t x = c.i;
    uint32_t r = (x + 0x7fffu + ((x >> 16) & 1u)) >> 16;
    return (ushort)r;
}

__device__ inline float wred_sum(float v) {
#pragma unroll
    for (int m = 32; m >= 1; m >>= 1) v += __shfl_xor(v, m, 64);
    return v;
}

__device__ inline float pick4(int h, float a, float b, float c, float d) {
    float ab = (h & 1) ? b : a;
    float cd = (h & 1) ? d : c;
    return (h & 2) ? cd : ab;
}

// ---------------- x -> bf16 (6.4M elements, 8/thread)
__global__ __launch_bounds__(256) void convert_x(const float* __restrict__ x,
                                                 ushort* __restrict__ xb) {
    int u = blockIdx.x * 256 + threadIdx.x;  // ushort8 unit
    const float4* x4 = (const float4*)x;
    float4 f0 = x4[u * 2];
    float4 f1 = x4[u * 2 + 1];
    short8 o;
    o[0] = (short)f2bf(f0.x); o[1] = (short)f2bf(f0.y);
    o[2] = (short)f2bf(f0.z); o[3] = (short)f2bf(f0.w);
    o[4] = (short)f2bf(f1.x); o[5] = (short)f2bf(f1.y);
    o[6] = (short)f2bf(f1.z); o[7] = (short)f2bf(f1.w);
    ((short8*)xb)[u] = o;
}

// ---------------- weights -> W^T bf16, pre-swizzled (16B unit u ^= n&7)
__global__ __launch_bounds__(256) void prep_weights(const float* __restrict__ W_node,
                                                    const float* __restrict__ W_gat,
                                                    ushort* __restrict__ WT) {
    int b = blockIdx.x;
    const float* W = (b == 0) ? W_node : (W_gat + (size_t)(b - 1) * 16384);
    ushort* D = WT + (size_t)b * 16384;
    int t = threadIdx.x;
    int n = t >> 1;
    int k0 = (t & 1) * 64;
    for (int kk = 0; kk < 64; kk++) {
        int k = k0 + kk;
        float v = W[k * 128 + n];
        int u = (k >> 3) ^ (n & 7);
        D[n * 128 + u * 8 + (k & 7)] = f2bf(v);
    }
}

// ---------------- MFMA GEMM
template <int MODE>
__global__ __launch_bounds__(256) void gemm_mfma(
    const ushort* __restrict__ Abf, const ushort* __restrict__ WT,
    ushort* __restrict__ out_bf, float* __restrict__ out_f32,
    const float* __restrict__ bias, const int* __restrict__ ntypes,
    const float* __restrict__ temb, int nrows) {
    __shared__ ushort wlds[16384];
    int tid = threadIdx.x;
    int lane = tid & 63;
    int wid = tid >> 6;

    {
        const short8* src = (const short8*)WT;
        short8* dst = (short8*)wlds;
#pragma unroll
        for (int i = 0; i < 8; i++) dst[i * 256 + tid] = src[i * 256 + tid];
    }

    int rbase = blockIdx.x * 64 + wid * 16;
    int arow = rbase + (lane & 15);
    if (arow >= nrows) arow = nrows - 1;
    const short8* arow_p = (const short8*)(Abf + (size_t)arow * 128);
    short8 afr[4];
#pragma unroll
    for (int ks = 0; ks < 4; ks++) afr[ks] = arow_p[ks * 4 + (lane >> 4)];

    __syncthreads();

    f32x4 acc[8];
#pragma unroll
    for (int i = 0; i < 8; i++) acc[i] = (f32x4){0.f, 0.f, 0.f, 0.f};

    int cgrp = lane & 15;
    int kgrp = lane >> 4;
#pragma unroll
    for (int ks = 0; ks < 4; ks++) {
        short8 a = afr[ks];
#pragma unroll
        for (int nt = 0; nt < 8; nt++) {
            int n = nt * 16 + cgrp;
            int u = (ks * 4 + kgrp) ^ (n & 7);
            short8 b = *(const short8*)&wlds[n * 128 + u * 8];
            acc[nt] = __builtin_amdgcn_mfma_f32_16x16x32_bf16(a, b, acc[nt], 0, 0, 0);
        }
    }

    int nts[4];
    if (MODE == 1) {
#pragma unroll
        for (int r = 0; r < 4; r++) {
            int row = rbase + kgrp * 4 + r;
            nts[r] = (row < nrows) ? ntypes[row] : 0;
        }
    }
#pragma unroll
    for (int nt = 0; nt < 8; nt++) {
        int colc = nt * 16 + cgrp;
#pragma unroll
        for (int r = 0; r < 4; r++) {
            int row = rbase + kgrp * 4 + r;
            if (row < nrows) {
                float v = acc[nt][r];
                if (MODE == 1) {
                    v += bias[colc] + temb[nts[r] * 128 + colc];
                    out_f32[(size_t)row * 128 + colc] = v;
                }
                out_bf[(size_t)row * 128 + colc] = f2bf(v);
            }
        }
    }
}

// ---------------- per-node attention scores s_src/s_dst [N,4]
__global__ __launch_bounds__(256) void attn_scores(
    const ushort* __restrict__ xh, const float* __restrict__ asrc,
    const float* __restrict__ adst, float* __restrict__ s_src,
    float* __restrict__ s_dst, int n) {
    int tid = threadIdx.x;
    int node = blockIdx.x * 2 + (tid >> 7);
    int c = tid & 127;
    if (node >= n) return;
    int h = c >> 5;
    int cc = c & 31;
    float v = bf2f(xh[(size_t)node * 128 + c]);
    float ps = v * asrc[h * 32 + cc];
    float pd = v * adst[h * 32 + cc];
#pragma unroll
    for (int m = 16; m >= 1; m >>= 1) {
        ps += __shfl_xor(ps, m, 64);
        pd += __shfl_xor(pd, m, 64);
    }
    if (cc == 0) {
        s_src[node * 4 + h] = ps;
        s_dst[node * 4 + h] = pd;
    }
}

// ---------------- CSR build
__global__ void count_edges(const int* __restrict__ dst, int* __restrict__ deg, int ne) {
    int i = blockIdx.x * blockDim.x + threadIdx.x;
    if (i < ne) atomicAdd(&deg[dst[i]], 1);
}

// 3-phase parallel scan over NN counts
__global__ __launch_bounds__(1024) void scan_local(const int* __restrict__ cnt,
                                                   int* __restrict__ rp,
                                                   int* __restrict__ btot, int n) {
    __shared__ int lds[1024];
    int t = threadIdx.x;
    int i = blockIdx.x * 1024 + t;
    int v = (i < n) ? cnt[i] : 0;
    lds[t] = v;
    __syncthreads();
    for (int off = 1; off < 1024; off <<= 1) {
        int u = (t >= off) ? lds[t - off] : 0;
        __syncthreads();
        lds[t] += u;
        __syncthreads();
    }
    if (i < n) rp[i] = lds[t] - v;  // local exclusive
    if (t == 1023) btot[blockIdx.x] = lds[1023];
}

__global__ __launch_bounds__(64) void scan_btot(int* __restrict__ btot) {
    int t = threadIdx.x;
    int v = (t < SNB) ? btot[t] : 0;
#pragma unroll
    for (int off = 1; off < 64; off <<= 1) {
        int u = __shfl_up(v, off, 64);
        if (t >= off) v += u;
    }
    if (t < SNB) btot[t] = v;  // inclusive prefix
}

__global__ __launch_bounds__(1024) void scan_add(int* __restrict__ rp,
                                                 const int* __restrict__ btot, int n) {
    int b = blockIdx.x;
    int i = b * 1024 + threadIdx.x;
    int add = (b == 0) ? 0 : btot[b - 1];
    if (i < n) rp[i] += add;
    if (i == 0) rp[n] = EE;
}

__global__ void fill_edges(const int* __restrict__ ei, const int* __restrict__ row_ptr,
                           int* __restrict__ fill, int* __restrict__ col, int ne) {
    int i = blockIdx.x * blockDim.x + threadIdx.x;
    if (i < ne) {
        int d = ei[ne + i];
        int pos = row_ptr[d] + atomicAdd(&fill[d], 1);
        col[pos] = ei[i];
    }
}

// ---------------- fused GAT aggregate + bias + layernorm + residual relu
// wave per node; SINGLE edge pass, no max-shift (scores bounded, fp32 exp safe):
// acc = sum(exp(e) * x), z = sum(exp(e)); msg = acc/z.
__global__ __launch_bounds__(256) void gat_aggregate(
    const ushort* __restrict__ xh, const float* __restrict__ ssrc,
    const float* __restrict__ sdst, const int* __restrict__ row_ptr,
    const int* __restrict__ col, const float* __restrict__ bg,
    const float* __restrict__ lng, const float* __restrict__ lnb,
    float* __restrict__ h, ushort* __restrict__ hb, int n) {
    int wid = threadIdx.x >> 6;
    int lane = threadIdx.x & 63;
    int node = blockIdx.x * 4 + wid;
    if (node >= n) return;

    int base = row_ptr[node];
    int deg = row_ptr[node + 1] - base;

    float4 sd = ((const float4*)sdst)[node];
    float4 ssf = ((const float4*)ssrc)[node];

    // lane = eg(0..3)*16 + g(0..15); lane owns channels [g*8, g*8+8), head = g>>2
    int eg = lane >> 4;
    int g = lane & 15;
    int head = g >> 2;
    float sdH = pick4(head, sd.x, sd.y, sd.z, sd.w);
    float esH = lrelu(pick4(head, ssf.x, ssf.y, ssf.z, ssf.w) + sdH);

    float acc[8];
#pragma unroll
    for (int k = 0; k < 8; k++) acc[k] = 0.f;
    float z = 0.f;

    if (eg == 0) {  // self-loop once
        float w = fexp(esH);
        z = w;
        short8 xv = *(const short8*)(xh + (size_t)node * 128 + g * 8);
#pragma unroll
        for (int k = 0; k < 8; k++) acc[k] += w * bf2f((ushort)xv[k]);
    }

    int nit = (deg + 3) >> 2;
#pragma unroll 2
    for (int t = 0; t < nit; t++) {
        int j = t * 4 + eg;
        if (j < deg) {
            int s = col[base + j];
            float4 ss = ((const float4*)ssrc)[s];
            float sH = pick4(head, ss.x, ss.y, ss.z, ss.w);
            float w = fexp(lrelu(sH + sdH));
            z += w;
            short8 xv = *(const short8*)(xh + (size_t)s * 128 + g * 8);
#pragma unroll
            for (int k = 0; k < 8; k++) acc[k] += w * bf2f((ushort)xv[k]);
        }
    }
    // reduce across the 4 edge groups (lanes differing in bits 4,5)
#pragma unroll
    for (int k = 0; k < 8; k++) {
        acc[k] += __shfl_xor(acc[k], 16, 64);
        acc[k] += __shfl_xor(acc[k], 32, 64);
    }
    z += __shfl_xor(z, 16, 64);
    z += __shfl_xor(z, 32, 64);
    float iz = 1.f / (z + 1e-16f);

    // bias + layernorm (channels replicated 4x across wave -> /512)
    const float4* bg4 = (const float4*)(bg + g * 8);
    float4 b0 = bg4[0], b1 = bg4[1];
    float o[8];
    o[0] = acc[0] * iz + b0.x; o[1] = acc[1] * iz + b0.y;
    o[2] = acc[2] * iz + b0.z; o[3] = acc[3] * iz + b0.w;
    o[4] = acc[4] * iz + b1.x; o[5] = acc[5] * iz + b1.y;
    o[6] = acc[6] * iz + b1.z; o[7] = acc[7] * iz + b1.w;

    float ls = 0.f;
#pragma unroll
    for (int k = 0; k < 8; k++) ls += o[k];
    float mu = wred_sum(ls) * (1.f / 512.f);
    float vs = 0.f;
#pragma unroll
    for (int k = 0; k < 8; k++) {
        o[k] -= mu;
        vs += o[k] * o[k];
    }
    float var = wred_sum(vs) * (1.f / 512.f);
    float rs = rsqrtf(var + 1e-5f);

    if (eg == 0) {
        const float4* lg4 = (const float4*)(lng + g * 8);
        const float4* lb4 = (const float4*)(lnb + g * 8);
        float4 g0 = lg4[0], g1 = lg4[1];
        float4 q0 = lb4[0], q1 = lb4[1];
        float* hr = h + (size_t)node * 128 + g * 8;
        float4* hr4 = (float4*)hr;
        float4 p0 = hr4[0], p1 = hr4[1];
        float y[8];
        y[0] = fmaxf(o[0] * rs * g0.x + q0.x + p0.x, 0.f);
        y[1] = fmaxf(o[1] * rs * g0.y + q0.y + p0.y, 0.f);
        y[2] = fmaxf(o[2] * rs * g0.z + q0.z + p0.z, 0.f);
        y[3] = fmaxf(o[3] * rs * g0.w + q0.w + p0.w, 0.f);
        y[4] = fmaxf(o[4] * rs * g1.x + q1.x + p1.x, 0.f);
        y[5] = fmaxf(o[5] * rs * g1.y + q1.y + p1.y, 0.f);
        y[6] = fmaxf(o[6] * rs * g1.z + q1.z + p1.z, 0.f);
        y[7] = fmaxf(o[7] * rs * g1.w + q1.w + p1.w, 0.f);
        float4 w0 = make_float4(y[0], y[1], y[2], y[3]);
        float4 w1 = make_float4(y[4], y[5], y[6], y[7]);
        hr4[0] = w0;
        hr4[1] = w1;
        short8 ob;
#pragma unroll
        for (int k = 0; k < 8; k++) ob[k] = (short)f2bf(y[k]);
        *(short8*)(hb + (size_t)node * 128 + g * 8) = ob;
    }
}

// ---------------- mean pool (batch sorted -> run-length atomics)
__global__ __launch_bounds__(256) void pool_kernel(const float* __restrict__ h,
                                                   const int* __restrict__ batch,
                                                   float* __restrict__ sums,
                                                   int* __restrict__ cnts, int n) {
    int c = threadIdx.x & 127;
    int half = threadIdx.x >> 7;
    int n0 = blockIdx.x * 64;
    float acc = 0.f;
    int cur = -1;
    for (int idx = half; idx < 64; idx += 2) {
        int node = n0 + idx;
        if (node >= n) break;
        int g = batch[node];
        if (g != cur) {
            if (cur >= 0) atomicAdd(&sums[cur * 128 + c], acc);
            cur = g;
            acc = 0.f;
        }
        acc += h[(size_t)node * 128 + c];
    }
    if (cur >= 0) atomicAdd(&sums[cur * 128 + c], acc);

    if (c == 0) {
        int cnt = 0, curg = -1;
        for (int idx = half; idx < 64; idx += 2) {
            int node = n0 + idx;
            if (node >= n) break;
            int g = batch[node];
            if (g != curg) {
                if (curg >= 0) atomicAdd(&cnts[curg], cnt);
                curg = g;
                cnt = 0;
            }
            cnt++;
        }
        if (curg >= 0) atomicAdd(&cnts[curg], cnt);
    }
}

// ---------------- MLP head: one block per graph
__global__ __launch_bounds__(256) void head_kernel(
    const float* __restrict__ sums, const int* __restrict__ cnts,
    const float* __restrict__ W1, const float* __restrict__ b1,
    const float* __restrict__ W2, const float* __restrict__ b2,
    const float* __restrict__ W3, const float* __restrict__ b3,
    float* __restrict__ out) {
    __shared__ float hg[128], z1[256], z2[128];
    int g = blockIdx.x;
    int t = threadIdx.x;
    if (t < 128) hg[t] = sums[g * 128 + t] / fmaxf((float)cnts[g], 1.f);
    __syncthreads();
    {
        float acc = b1[t];
        for (int k = 0; k < 128; k++) acc += hg[k] * W1[k * 256 + t];
        z1[t] = fmaxf(acc, 0.f);
    }
    __syncthreads();
    if (t < 128) {
        float acc = b2[t];
        for (int k = 0; k < 256; k++) acc += z1[k] * W2[k * 128 + t];
        z2[t] = fmaxf(acc, 0.f);
    }
    __syncthreads();
    if (t < NCLS) {
        float acc = b3[t];
        for (int k = 0; k < 128; k++) acc += z2[k] * W3[k * NCLS + t];
        out[g * NCLS + t] = acc;
    }
}

extern "C" void kernel_launch(void* const* d_in, const int* in_sizes, int n_in,
                              void* d_out, int out_size, void* d_ws, size_t ws_size,
                              hipStream_t stream) {
    const float* x = (const float*)d_in[0];
    const int* ei = (const int*)d_in[1];
    const int* ntypes = (const int*)d_in[2];
    const int* batch = (const int*)d_in[3];
    const float* W_node = (const float*)d_in[4];
    const float* b_node = (const float*)d_in[5];
    const float* temb = (const float*)d_in[6];
    const float* W_gat = (const float*)d_in[7];
    const float* a_src = (const float*)d_in[8];
    const float* a_dst = (const float*)d_in[9];
    const float* b_gat = (const float*)d_in[10];
    const float* ln_g = (const float*)d_in[11];
    const float* ln_b = (const float*)d_in[12];
    const float* W1 = (const float*)d_in[13];
    const float* b1 = (const float*)d_in[14];
    const float* W2 = (const float*)d_in[15];
    const float* b2 = (const float*)d_in[16];
    const float* W3 = (const float*)d_in[17];
    const float* b3 = (const float*)d_in[18];
    float* out = (float*)d_out;

    char* ws = (char*)d_ws;
    size_t off = 0;
    auto alloc = [&](size_t bytes) {
        void* p = ws + off;
        off += (bytes + 255) & ~(size_t)255;
        return p;
    };
    float* h = (float*)alloc((size_t)NN * 128 * 4);
    ushort* hb = (ushort*)alloc((size_t)NN * 128 * 2);
    ushort* xhb = (ushort*)alloc((size_t)NN * 128 * 2);
    ushort* WT = (ushort*)alloc((size_t)4 * 16384 * 2);
    float* ssrc = (float*)alloc((size_t)NN * 4 * 4);
    float* sdst = (float*)alloc((size_t)NN * 4 * 4);
    int* rowp = (int*)alloc((size_t)(NN + 1) * 4);
    int* fillc = (int*)alloc((size_t)NN * 4);
    int* col = (int*)alloc((size_t)EE * 4);
    float* psum = (float*)alloc((size_t)NGRAPH * 128 * 4);
    int* pcnt = (int*)alloc((size_t)NGRAPH * 4);
    int* btot = (int*)alloc((size_t)SNB * 4);

    hipError_t e0;
    e0 = hipMemsetAsync(fillc, 0, (size_t)NN * 4, stream); (void)e0;
    e0 = hipMemsetAsync(psum, 0, (size_t)NGRAPH * 128 * 4, stream); (void)e0;
    e0 = hipMemsetAsync(pcnt, 0, (size_t)NGRAPH * 4, stream); (void)e0;

    // prep: x -> bf16 (into xhb), weights -> W^T bf16 swizzled
    convert_x<<<3125, 256, 0, stream>>>(x, xhb);
    prep_weights<<<4, 256, 0, stream>>>(W_node, W_gat, WT);

    // CSR build (parallel scan)
    count_edges<<<(EE + 255) / 256, 256, 0, stream>>>(ei + EE, fillc, EE);
    scan_local<<<SNB, 1024, 0, stream>>>(fillc, rowp, btot, NN);
    scan_btot<<<1, 64, 0, stream>>>(btot);
    scan_add<<<SNB, 1024, 0, stream>>>(rowp, btot, NN);
    e0 = hipMemsetAsync(fillc, 0, (size_t)NN * 4, stream); (void)e0;
    fill_edges<<<(EE + 255) / 256, 256, 0, stream>>>(ei, rowp, fillc, col, EE);

    // node init: h = x@W_node + b_node + temb[ntypes]  (fp32 + bf16)
    int gemm_grid = (NN + 63) / 64;
    gemm_mfma<1><<<gemm_grid, 256, 0, stream>>>(xhb, WT, hb, h, b_node, ntypes, temb, NN);

    for (int l = 0; l < LL; l++) {
        gemm_mfma<0><<<gemm_grid, 256, 0, stream>>>(hb, WT + (size_t)(l + 1) * 16384, xhb,
                                                    nullptr, nullptr, nullptr, nullptr, NN);
        attn_scores<<<(NN + 1) / 2, 256, 0, stream>>>(xhb, a_src + l * HEADS * CC,
                                                      a_dst + l * HEADS * CC, ssrc, sdst, NN);
        gat_aggregate<<<(NN + 3) / 4, 256, 0, stream>>>(
            xhb, ssrc, sdst, rowp, col, b_gat + l * 128, ln_g + l * 128, ln_b + l * 128,
            h, hb, NN);
    }

    pool_kernel<<<(NN + 63) / 64, 256, 0, stream>>>(h, batch, psum, pcnt, NN);
    head_kernel<<<NGRAPH, 256, 0, stream>>>(psum, pcnt, W1, b1, W2, b2, W3, b3, out);
}

// Round 7
// 366.130 us; speedup vs baseline: 3.2307x; 1.0906x over previous
//
#include <hip/hip_runtime.h>
#include <hip/hip_bf16.h>

#define NN 50000
#define EE 800000
#define IN_DIM 128
#define HH 128
#define HEADS 4
#define CC 32
#define LL 3
#define NCLS 10
#define NGRAPH 64
#define SNB ((NN + 1023) / 1024)  // 49 scan blocks

using short8 = __attribute__((ext_vector_type(8))) short;
using f32x4 = __attribute__((ext_vector_type(4))) float;

__device__ inline float lrelu(float x) { return fmaxf(x, 0.2f * x); }
__device__ inline float fexp(float x) { return __expf(x); }

__device__ inline float bf2f(ushort u) {
    union { uint32_t i; float f; } c;
    c.i = ((uint32_t)u) << 16;
    return c.f;
}
__device__ inline ushort f2bf(float f) {
    union { float f; uint32_t i; } c;
    c.f = f;
    uint32_t x = c.i;
    uint32_t r = (x + 0x7fffu + ((x >> 16) & 1u)) >> 16;
    return (ushort)r;
}

__device__ inline float wred_sum(float v) {
#pragma unroll
    for (int m = 32; m >= 1; m >>= 1) v += __shfl_xor(v, m, 64);
    return v;
}

__device__ inline float pick4(int h, float a, float b, float c, float d) {
    float ab = (h & 1) ? b : a;
    float cd = (h & 1) ? d : c;
    return (h & 2) ? cd : ab;
}

// ---------------- x -> bf16 (6.4M elements, 8/thread)
__global__ __launch_bounds__(256) void convert_x(const float* __restrict__ x,
                                                 ushort* __restrict__ xb) {
    int u = blockIdx.x * 256 + threadIdx.x;  // ushort8 unit
    const float4* x4 = (const float4*)x;
    float4 f0 = x4[u * 2];
    float4 f1 = x4[u * 2 + 1];
    short8 o;
    o[0] = (short)f2bf(f0.x); o[1] = (short)f2bf(f0.y);
    o[2] = (short)f2bf(f0.z); o[3] = (short)f2bf(f0.w);
    o[4] = (short)f2bf(f1.x); o[5] = (short)f2bf(f1.y);
    o[6] = (short)f2bf(f1.z); o[7] = (short)f2bf(f1.w);
    ((short8*)xb)[u] = o;
}

// ---------------- weights -> W^T bf16, pre-swizzled (16B unit u ^= n&7)
__global__ __launch_bounds__(256) void prep_weights(const float* __restrict__ W_node,
                                                    const float* __restrict__ W_gat,
                                                    ushort* __restrict__ WT) {
    int b = blockIdx.x;
    const float* W = (b == 0) ? W_node : (W_gat + (size_t)(b - 1) * 16384);
    ushort* D = WT + (size_t)b * 16384;
    int t = threadIdx.x;
    int n = t >> 1;
    int k0 = (t & 1) * 64;
    for (int kk = 0; kk < 64; kk++) {
        int k = k0 + kk;
        float v = W[k * 128 + n];
        int u = (k >> 3) ^ (n & 7);
        D[n * 128 + u * 8 + (k & 7)] = f2bf(v);
    }
}

// ---------------- MFMA GEMM: out_bf[N,128] = A_bf16[N,128] @ W
// MODE 0: plain. MODE 1: + b_node + temb[ntypes] epilogue.
template <int MODE>
__global__ __launch_bounds__(256) void gemm_mfma(
    const ushort* __restrict__ Abf, const ushort* __restrict__ WT,
    ushort* __restrict__ out_bf,
    const float* __restrict__ bias, const int* __restrict__ ntypes,
    const float* __restrict__ temb, int nrows) {
    __shared__ ushort wlds[16384];
    int tid = threadIdx.x;
    int lane = tid & 63;
    int wid = tid >> 6;

    {
        const short8* src = (const short8*)WT;
        short8* dst = (short8*)wlds;
#pragma unroll
        for (int i = 0; i < 8; i++) dst[i * 256 + tid] = src[i * 256 + tid];
    }

    int rbase = blockIdx.x * 64 + wid * 16;
    int arow = rbase + (lane & 15);
    if (arow >= nrows) arow = nrows - 1;
    const short8* arow_p = (const short8*)(Abf + (size_t)arow * 128);
    short8 afr[4];
#pragma unroll
    for (int ks = 0; ks < 4; ks++) afr[ks] = arow_p[ks * 4 + (lane >> 4)];

    __syncthreads();

    f32x4 acc[8];
#pragma unroll
    for (int i = 0; i < 8; i++) acc[i] = (f32x4){0.f, 0.f, 0.f, 0.f};

    int cgrp = lane & 15;
    int kgrp = lane >> 4;
#pragma unroll
    for (int ks = 0; ks < 4; ks++) {
        short8 a = afr[ks];
#pragma unroll
        for (int nt = 0; nt < 8; nt++) {
            int n = nt * 16 + cgrp;
            int u = (ks * 4 + kgrp) ^ (n & 7);
            short8 b = *(const short8*)&wlds[n * 128 + u * 8];
            acc[nt] = __builtin_amdgcn_mfma_f32_16x16x32_bf16(a, b, acc[nt], 0, 0, 0);
        }
    }

    int nts[4];
    if (MODE == 1) {
#pragma unroll
        for (int r = 0; r < 4; r++) {
            int row = rbase + kgrp * 4 + r;
            nts[r] = (row < nrows) ? ntypes[row] : 0;
        }
    }
#pragma unroll
    for (int nt = 0; nt < 8; nt++) {
        int colc = nt * 16 + cgrp;
#pragma unroll
        for (int r = 0; r < 4; r++) {
            int row = rbase + kgrp * 4 + r;
            if (row < nrows) {
                float v = acc[nt][r];
                if (MODE == 1) v += bias[colc] + temb[nts[r] * 128 + colc];
                out_bf[(size_t)row * 128 + colc] = f2bf(v);
            }
        }
    }
}

// ---------------- per-node attention scores s_src/s_dst [N,4]
// 16 lanes per node; lane g owns channels [g*8, g*8+8), head = g>>2.
// asrc/adst are channel-linear (head*32+cc == channel index).
__global__ __launch_bounds__(256) void attn_scores(
    const ushort* __restrict__ xh, const float* __restrict__ asrc,
    const float* __restrict__ adst, float* __restrict__ s_src,
    float* __restrict__ s_dst, int n) {
    int tid = threadIdx.x;
    int node = blockIdx.x * 16 + (tid >> 4);
    int g = tid & 15;
    if (node >= n) return;
    short8 xv = *(const short8*)(xh + (size_t)node * 128 + g * 8);
    const float4* as4 = (const float4*)(asrc + g * 8);
    const float4* ad4 = (const float4*)(adst + g * 8);
    float4 a0 = as4[0], a1 = as4[1];
    float4 d0 = ad4[0], d1 = ad4[1];
    float xf[8];
#pragma unroll
    for (int k = 0; k < 8; k++) xf[k] = bf2f((ushort)xv[k]);
    float ps = xf[0] * a0.x + xf[1] * a0.y + xf[2] * a0.z + xf[3] * a0.w +
               xf[4] * a1.x + xf[5] * a1.y + xf[6] * a1.z + xf[7] * a1.w;
    float pd = xf[0] * d0.x + xf[1] * d0.y + xf[2] * d0.z + xf[3] * d0.w +
               xf[4] * d1.x + xf[5] * d1.y + xf[6] * d1.z + xf[7] * d1.w;
    ps += __shfl_xor(ps, 1, 64); ps += __shfl_xor(ps, 2, 64);
    pd += __shfl_xor(pd, 1, 64); pd += __shfl_xor(pd, 2, 64);
    if ((g & 3) == 0) {
        s_src[node * 4 + (g >> 2)] = ps;
        s_dst[node * 4 + (g >> 2)] = pd;
    }
}

// ---------------- CSR build
__global__ void count_edges(const int* __restrict__ dst, int* __restrict__ deg, int ne) {
    int i = blockIdx.x * blockDim.x + threadIdx.x;
    if (i < ne) atomicAdd(&deg[dst[i]], 1);
}

__global__ __launch_bounds__(1024) void scan_local(const int* __restrict__ cnt,
                                                   int* __restrict__ rp,
                                                   int* __restrict__ btot, int n) {
    __shared__ int lds[1024];
    int t = threadIdx.x;
    int i = blockIdx.x * 1024 + t;
    int v = (i < n) ? cnt[i] : 0;
    lds[t] = v;
    __syncthreads();
    for (int off = 1; off < 1024; off <<= 1) {
        int u = (t >= off) ? lds[t - off] : 0;
        __syncthreads();
        lds[t] += u;
        __syncthreads();
    }
    if (i < n) rp[i] = lds[t] - v;  // local exclusive
    if (t == 1023) btot[blockIdx.x] = lds[1023];
}

__global__ __launch_bounds__(64) void scan_btot(int* __restrict__ btot) {
    int t = threadIdx.x;
    int v = (t < SNB) ? btot[t] : 0;
#pragma unroll
    for (int off = 1; off < 64; off <<= 1) {
        int u = __shfl_up(v, off, 64);
        if (t >= off) v += u;
    }
    if (t < SNB) btot[t] = v;  // inclusive prefix
}

__global__ __launch_bounds__(1024) void scan_add(int* __restrict__ rp,
                                                 const int* __restrict__ btot, int n) {
    int b = blockIdx.x;
    int i = b * 1024 + threadIdx.x;
    int add = (b == 0) ? 0 : btot[b - 1];
    if (i < n) rp[i] += add;
    if (i == 0) rp[n] = EE;
}

__global__ void fill_edges(const int* __restrict__ ei, const int* __restrict__ row_ptr,
                           int* __restrict__ fill, int* __restrict__ col, int ne) {
    int i = blockIdx.x * blockDim.x + threadIdx.x;
    if (i < ne) {
        int d = ei[ne + i];
        int pos = row_ptr[d] + atomicAdd(&fill[d], 1);
        col[pos] = ei[i];
    }
}

// ---------------- fused GAT aggregate + bias + layernorm + residual relu
// wave per node; single edge pass (no max-shift), bf16 h in-place residual.
__global__ __launch_bounds__(256) void gat_aggregate(
    const ushort* __restrict__ xh, const float* __restrict__ ssrc,
    const float* __restrict__ sdst, const int* __restrict__ row_ptr,
    const int* __restrict__ col, const float* __restrict__ bg,
    const float* __restrict__ lng, const float* __restrict__ lnb,
    ushort* __restrict__ h, int n) {
    int wid = threadIdx.x >> 6;
    int lane = threadIdx.x & 63;
    int node = blockIdx.x * 4 + wid;
    if (node >= n) return;

    int base = row_ptr[node];
    int deg = row_ptr[node + 1] - base;

    float4 sd = ((const float4*)sdst)[node];
    float4 ssf = ((const float4*)ssrc)[node];

    // lane = eg(0..3)*16 + g(0..15); lane owns channels [g*8, g*8+8), head = g>>2
    int eg = lane >> 4;
    int g = lane & 15;
    int head = g >> 2;
    float sdH = pick4(head, sd.x, sd.y, sd.z, sd.w);
    float esH = lrelu(pick4(head, ssf.x, ssf.y, ssf.z, ssf.w) + sdH);

    float acc[8];
#pragma unroll
    for (int k = 0; k < 8; k++) acc[k] = 0.f;
    float z = 0.f;

    if (eg == 0) {  // self-loop once
        float w = fexp(esH);
        z = w;
        short8 xv = *(const short8*)(xh + (size_t)node * 128 + g * 8);
#pragma unroll
        for (int k = 0; k < 8; k++) acc[k] += w * bf2f((ushort)xv[k]);
    }

    int nit = (deg + 3) >> 2;
#pragma unroll 2
    for (int t = 0; t < nit; t++) {
        int j = t * 4 + eg;
        if (j < deg) {
            int s = col[base + j];
            float4 ss = ((const float4*)ssrc)[s];
            float sH = pick4(head, ss.x, ss.y, ss.z, ss.w);
            float w = fexp(lrelu(sH + sdH));
            z += w;
            short8 xv = *(const short8*)(xh + (size_t)s * 128 + g * 8);
#pragma unroll
            for (int k = 0; k < 8; k++) acc[k] += w * bf2f((ushort)xv[k]);
        }
    }
#pragma unroll
    for (int k = 0; k < 8; k++) {
        acc[k] += __shfl_xor(acc[k], 16, 64);
        acc[k] += __shfl_xor(acc[k], 32, 64);
    }
    z += __shfl_xor(z, 16, 64);
    z += __shfl_xor(z, 32, 64);
    float iz = 1.f / (z + 1e-16f);

    // bias + layernorm (channels replicated 4x across wave -> /512)
    const float4* bg4 = (const float4*)(bg + g * 8);
    float4 b0 = bg4[0], b1 = bg4[1];
    float o[8];
    o[0] = acc[0] * iz + b0.x; o[1] = acc[1] * iz + b0.y;
    o[2] = acc[2] * iz + b0.z; o[3] = acc[3] * iz + b0.w;
    o[4] = acc[4] * iz + b1.x; o[5] = acc[5] * iz + b1.y;
    o[6] = acc[6] * iz + b1.z; o[7] = acc[7] * iz + b1.w;

    float ls = 0.f;
#pragma unroll
    for (int k = 0; k < 8; k++) ls += o[k];
    float mu = wred_sum(ls) * (1.f / 512.f);
    float vs = 0.f;
#pragma unroll
    for (int k = 0; k < 8; k++) {
        o[k] -= mu;
        vs += o[k] * o[k];
    }
    float var = wred_sum(vs) * (1.f / 512.f);
    float rs = rsqrtf(var + 1e-5f);

    if (eg == 0) {
        const float4* lg4 = (const float4*)(lng + g * 8);
        const float4* lb4 = (const float4*)(lnb + g * 8);
        float4 g0 = lg4[0], g1 = lg4[1];
        float4 q0 = lb4[0], q1 = lb4[1];
        ushort* hr = h + (size_t)node * 128 + g * 8;
        short8 prev = *(const short8*)hr;
        float y[8];
        y[0] = fmaxf(o[0] * rs * g0.x + q0.x + bf2f((ushort)prev[0]), 0.f);
        y[1] = fmaxf(o[1] * rs * g0.y + q0.y + bf2f((ushort)prev[1]), 0.f);
        y[2] = fmaxf(o[2] * rs * g0.z + q0.z + bf2f((ushort)prev[2]), 0.f);
        y[3] = fmaxf(o[3] * rs * g0.w + q0.w + bf2f((ushort)prev[3]), 0.f);
        y[4] = fmaxf(o[4] * rs * g1.x + q1.x + bf2f((ushort)prev[4]), 0.f);
        y[5] = fmaxf(o[5] * rs * g1.y + q1.y + bf2f((ushort)prev[5]), 0.f);
        y[6] = fmaxf(o[6] * rs * g1.z + q1.z + bf2f((ushort)prev[6]), 0.f);
        y[7] = fmaxf(o[7] * rs * g1.w + q1.w + bf2f((ushort)prev[7]), 0.f);
        short8 ob;
#pragma unroll
        for (int k = 0; k < 8; k++) ob[k] = (short)f2bf(y[k]);
        *(short8*)hr = ob;
    }
}

// ---------------- mean pool (batch sorted -> run-length atomics), bf16 h
__global__ __launch_bounds__(256) void pool_kernel(const ushort* __restrict__ h,
                                                   const int* __restrict__ batch,
                                                   float* __restrict__ sums,
                                                   int* __restrict__ cnts, int n) {
    int c = threadIdx.x & 127;
    int half = threadIdx.x >> 7;
    int n0 = blockIdx.x * 64;
    float acc = 0.f;
    int cur = -1;
    for (int idx = half; idx < 64; idx += 2) {
        int node = n0 + idx;
        if (node >= n) break;
        int g = batch[node];
        if (g != cur) {
            if (cur >= 0) atomicAdd(&sums[cur * 128 + c], acc);
            cur = g;
            acc = 0.f;
        }
        acc += bf2f(h[(size_t)node * 128 + c]);
    }
    if (cur >= 0) atomicAdd(&sums[cur * 128 + c], acc);

    if (c == 0) {
        int cnt = 0, curg = -1;
        for (int idx = half; idx < 64; idx += 2) {
            int node = n0 + idx;
            if (node >= n) break;
            int g = batch[node];
            if (g != curg) {
                if (curg >= 0) atomicAdd(&cnts[curg], cnt);
                curg = g;
                cnt = 0;
            }
            cnt++;
        }
        if (curg >= 0) atomicAdd(&cnts[curg], cnt);
    }
}

// ---------------- MLP head: one block per graph
__global__ __launch_bounds__(256) void head_kernel(
    const float* __restrict__ sums, const int* __restrict__ cnts,
    const float* __restrict__ W1, const float* __restrict__ b1,
    const float* __restrict__ W2, const float* __restrict__ b2,
    const float* __restrict__ W3, const float* __restrict__ b3,
    float* __restrict__ out) {
    __shared__ float hg[128], z1[256], z2[128];
    int g = blockIdx.x;
    int t = threadIdx.x;
    if (t < 128) hg[t] = sums[g * 128 + t] / fmaxf((float)cnts[g], 1.f);
    __syncthreads();
    {
        float acc = b1[t];
        for (int k = 0; k < 128; k++) acc += hg[k] * W1[k * 256 + t];
        z1[t] = fmaxf(acc, 0.f);
    }
    __syncthreads();
    if (t < 128) {
        float acc = b2[t];
        for (int k = 0; k < 256; k++) acc += z1[k] * W2[k * 128 + t];
        z2[t] = fmaxf(acc, 0.f);
    }
    __syncthreads();
    if (t < NCLS) {
        float acc = b3[t];
        for (int k = 0; k < 128; k++) acc += z2[k] * W3[k * NCLS + t];
        out[g * NCLS + t] = acc;
    }
}

extern "C" void kernel_launch(void* const* d_in, const int* in_sizes, int n_in,
                              void* d_out, int out_size, void* d_ws, size_t ws_size,
                              hipStream_t stream) {
    const float* x = (const float*)d_in[0];
    const int* ei = (const int*)d_in[1];
    const int* ntypes = (const int*)d_in[2];
    const int* batch = (const int*)d_in[3];
    const float* W_node = (const float*)d_in[4];
    const float* b_node = (const float*)d_in[5];
    const float* temb = (const float*)d_in[6];
    const float* W_gat = (const float*)d_in[7];
    const float* a_src = (const float*)d_in[8];
    const float* a_dst = (const float*)d_in[9];
    const float* b_gat = (const float*)d_in[10];
    const float* ln_g = (const float*)d_in[11];
    const float* ln_b = (const float*)d_in[12];
    const float* W1 = (const float*)d_in[13];
    const float* b1 = (const float*)d_in[14];
    const float* W2 = (const float*)d_in[15];
    const float* b2 = (const float*)d_in[16];
    const float* W3 = (const float*)d_in[17];
    const float* b3 = (const float*)d_in[18];
    float* out = (float*)d_out;

    char* ws = (char*)d_ws;
    size_t off = 0;
    auto alloc = [&](size_t bytes) {
        void* p = ws + off;
        off += (bytes + 255) & ~(size_t)255;
        return p;
    };
    ushort* hb = (ushort*)alloc((size_t)NN * 128 * 2);   // bf16 h
    ushort* xhb = (ushort*)alloc((size_t)NN * 128 * 2);  // bf16 xh; aliases x_bf16
    ushort* WT = (ushort*)alloc((size_t)4 * 16384 * 2);
    float* ssrc = (float*)alloc((size_t)NN * 4 * 4);
    float* sdst = (float*)alloc((size_t)NN * 4 * 4);
    int* rowp = (int*)alloc((size_t)(NN + 1) * 4);
    int* fillc = (int*)alloc((size_t)NN * 4);
    int* col = (int*)alloc((size_t)EE * 4);
    float* psum = (float*)alloc((size_t)NGRAPH * 128 * 4);
    int* pcnt = (int*)alloc((size_t)NGRAPH * 4);
    int* btot = (int*)alloc((size_t)SNB * 4);

    hipError_t e0;
    e0 = hipMemsetAsync(fillc, 0, (size_t)NN * 4, stream); (void)e0;
    e0 = hipMemsetAsync(psum, 0, (size_t)NGRAPH * 128 * 4, stream); (void)e0;
    e0 = hipMemsetAsync(pcnt, 0, (size_t)NGRAPH * 4, stream); (void)e0;

    // prep: x -> bf16 (into xhb), weights -> W^T bf16 swizzled
    convert_x<<<3125, 256, 0, stream>>>(x, xhb);
    prep_weights<<<4, 256, 0, stream>>>(W_node, W_gat, WT);

    // CSR build (parallel scan)
    count_edges<<<(EE + 255) / 256, 256, 0, stream>>>(ei + EE, fillc, EE);
    scan_local<<<SNB, 1024, 0, stream>>>(fillc, rowp, btot, NN);
    scan_btot<<<1, 64, 0, stream>>>(btot);
    scan_add<<<SNB, 1024, 0, stream>>>(rowp, btot, NN);
    e0 = hipMemsetAsync(fillc, 0, (size_t)NN * 4, stream); (void)e0;
    fill_edges<<<(EE + 255) / 256, 256, 0, stream>>>(ei, rowp, fillc, col, EE);

    // node init: h = x@W_node + b_node + temb[ntypes]  (bf16)
    int gemm_grid = (NN + 63) / 64;
    gemm_mfma<1><<<gemm_grid, 256, 0, stream>>>(xhb, WT, hb, b_node, ntypes, temb, NN);

    for (int l = 0; l < LL; l++) {
        gemm_mfma<0><<<gemm_grid, 256, 0, stream>>>(hb, WT + (size_t)(l + 1) * 16384, xhb,
                                                    nullptr, nullptr, nullptr, NN);
        attn_scores<<<(NN + 15) / 16, 256, 0, stream>>>(xhb, a_src + l * HEADS * CC,
                                                        a_dst + l * HEADS * CC, ssrc, sdst, NN);
        gat_aggregate<<<(NN + 3) / 4, 256, 0, stream>>>(
            xhb, ssrc, sdst, rowp, col, b_gat + l * 128, ln_g + l * 128, ln_b + l * 128,
            hb, NN);
    }

    pool_kernel<<<(NN + 63) / 64, 256, 0, stream>>>(hb, batch, psum, pcnt, NN);
    head_kernel<<<NGRAPH, 256, 0, stream>>>(psum, pcnt, W1, b1, W2, b2, W3, b3, out);
}

// Round 8
// 347.120 us; speedup vs baseline: 3.4076x; 1.0548x over previous
//
#include <hip/hip_runtime.h>
#include <hip/hip_bf16.h>

#define NN 50000
#define EE 800000
#define IN_DIM 128
#define HH 128
#define HEADS 4
#define CC 32
#define LL 3
#define NCLS 10
#define NGRAPH 64
#define SNB ((NN + 1023) / 1024)  // 49 scan blocks

using short8 = __attribute__((ext_vector_type(8))) short;
using f32x4 = __attribute__((ext_vector_type(4))) float;

__device__ inline float lrelu(float x) { return fmaxf(x, 0.2f * x); }
__device__ inline float fexp(float x) { return __expf(x); }

__device__ inline float bf2f(ushort u) {
    union { uint32_t i; float f; } c;
    c.i = ((uint32_t)u) << 16;
    return c.f;
}
__device__ inline ushort f2bf(float f) {
    union { float f; uint32_t i; } c;
    c.f = f;
    uint32_t x = c.i;
    uint32_t r = (x + 0x7fffu + ((x >> 16) & 1u)) >> 16;
    return (ushort)r;
}

__device__ inline float wred_sum(float v) {
#pragma unroll
    for (int m = 32; m >= 1; m >>= 1) v += __shfl_xor(v, m, 64);
    return v;
}

__device__ inline float pick4(int h, float a, float b, float c, float d) {
    float ab = (h & 1) ? b : a;
    float cd = (h & 1) ? d : c;
    return (h & 2) ? cd : ab;
}

// ---------------- x -> bf16 (6.4M elements, 8/thread)
__global__ __launch_bounds__(256) void convert_x(const float* __restrict__ x,
                                                 ushort* __restrict__ xb) {
    int u = blockIdx.x * 256 + threadIdx.x;  // ushort8 unit
    const float4* x4 = (const float4*)x;
    float4 f0 = x4[u * 2];
    float4 f1 = x4[u * 2 + 1];
    short8 o;
    o[0] = (short)f2bf(f0.x); o[1] = (short)f2bf(f0.y);
    o[2] = (short)f2bf(f0.z); o[3] = (short)f2bf(f0.w);
    o[4] = (short)f2bf(f1.x); o[5] = (short)f2bf(f1.y);
    o[6] = (short)f2bf(f1.z); o[7] = (short)f2bf(f1.w);
    ((short8*)xb)[u] = o;
}

// ---------------- weights -> W^T bf16, pre-swizzled (16B unit u ^= n&7)
__global__ __launch_bounds__(256) void prep_weights(const float* __restrict__ W_node,
                                                    const float* __restrict__ W_gat,
                                                    ushort* __restrict__ WT) {
    int b = blockIdx.x;
    const float* W = (b == 0) ? W_node : (W_gat + (size_t)(b - 1) * 16384);
    ushort* D = WT + (size_t)b * 16384;
    int t = threadIdx.x;
    int n = t >> 1;
    int k0 = (t & 1) * 64;
    for (int kk = 0; kk < 64; kk++) {
        int k = k0 + kk;
        float v = W[k * 128 + n];
        int u = (k >> 3) ^ (n & 7);
        D[n * 128 + u * 8 + (k & 7)] = f2bf(v);
    }
}

// ---------------- MFMA GEMM: out_bf[N,128] = A_bf16[N,128] @ W
template <int MODE>
__global__ __launch_bounds__(256) void gemm_mfma(
    const ushort* __restrict__ Abf, const ushort* __restrict__ WT,
    ushort* __restrict__ out_bf,
    const float* __restrict__ bias, const int* __restrict__ ntypes,
    const float* __restrict__ temb, int nrows) {
    __shared__ ushort wlds[16384];
    int tid = threadIdx.x;
    int lane = tid & 63;
    int wid = tid >> 6;

    {
        const short8* src = (const short8*)WT;
        short8* dst = (short8*)wlds;
#pragma unroll
        for (int i = 0; i < 8; i++) dst[i * 256 + tid] = src[i * 256 + tid];
    }

    int rbase = blockIdx.x * 64 + wid * 16;
    int arow = rbase + (lane & 15);
    if (arow >= nrows) arow = nrows - 1;
    const short8* arow_p = (const short8*)(Abf + (size_t)arow * 128);
    short8 afr[4];
#pragma unroll
    for (int ks = 0; ks < 4; ks++) afr[ks] = arow_p[ks * 4 + (lane >> 4)];

    __syncthreads();

    f32x4 acc[8];
#pragma unroll
    for (int i = 0; i < 8; i++) acc[i] = (f32x4){0.f, 0.f, 0.f, 0.f};

    int cgrp = lane & 15;
    int kgrp = lane >> 4;
#pragma unroll
    for (int ks = 0; ks < 4; ks++) {
        short8 a = afr[ks];
#pragma unroll
        for (int nt = 0; nt < 8; nt++) {
            int n = nt * 16 + cgrp;
            int u = (ks * 4 + kgrp) ^ (n & 7);
            short8 b = *(const short8*)&wlds[n * 128 + u * 8];
            acc[nt] = __builtin_amdgcn_mfma_f32_16x16x32_bf16(a, b, acc[nt], 0, 0, 0);
        }
    }

    int nts[4];
    if (MODE == 1) {
#pragma unroll
        for (int r = 0; r < 4; r++) {
            int row = rbase + kgrp * 4 + r;
            nts[r] = (row < nrows) ? ntypes[row] : 0;
        }
    }
#pragma unroll
    for (int nt = 0; nt < 8; nt++) {
        int colc = nt * 16 + cgrp;
#pragma unroll
        for (int r = 0; r < 4; r++) {
            int row = rbase + kgrp * 4 + r;
            if (row < nrows) {
                float v = acc[nt][r];
                if (MODE == 1) v += bias[colc] + temb[nts[r] * 128 + colc];
                out_bf[(size_t)row * 128 + colc] = f2bf(v);
            }
        }
    }
}

// ---------------- per-node attention scores s_src/s_dst [N,4]
__global__ __launch_bounds__(256) void attn_scores(
    const ushort* __restrict__ xh, const float* __restrict__ asrc,
    const float* __restrict__ adst, float* __restrict__ s_src,
    float* __restrict__ s_dst, int n) {
    int tid = threadIdx.x;
    int node = blockIdx.x * 16 + (tid >> 4);
    int g = tid & 15;
    if (node >= n) return;
    short8 xv = *(const short8*)(xh + (size_t)node * 128 + g * 8);
    const float4* as4 = (const float4*)(asrc + g * 8);
    const float4* ad4 = (const float4*)(adst + g * 8);
    float4 a0 = as4[0], a1 = as4[1];
    float4 d0 = ad4[0], d1 = ad4[1];
    float xf[8];
#pragma unroll
    for (int k = 0; k < 8; k++) xf[k] = bf2f((ushort)xv[k]);
    float ps = xf[0] * a0.x + xf[1] * a0.y + xf[2] * a0.z + xf[3] * a0.w +
               xf[4] * a1.x + xf[5] * a1.y + xf[6] * a1.z + xf[7] * a1.w;
    float pd = xf[0] * d0.x + xf[1] * d0.y + xf[2] * d0.z + xf[3] * d0.w +
               xf[4] * d1.x + xf[5] * d1.y + xf[6] * d1.z + xf[7] * d1.w;
    ps += __shfl_xor(ps, 1, 64); ps += __shfl_xor(ps, 2, 64);
    pd += __shfl_xor(pd, 1, 64); pd += __shfl_xor(pd, 2, 64);
    if ((g & 3) == 0) {
        s_src[node * 4 + (g >> 2)] = ps;
        s_dst[node * 4 + (g >> 2)] = pd;
    }
}

// ---------------- CSR build: pass A = count + slot, pass B = non-atomic fill
__global__ void count_slot(const int* __restrict__ dst, int* __restrict__ deg,
                           int* __restrict__ slot, int ne) {
    int i = blockIdx.x * blockDim.x + threadIdx.x;
    if (i < ne) slot[i] = atomicAdd(&deg[dst[i]], 1);
}

__global__ __launch_bounds__(1024) void scan_local(const int* __restrict__ cnt,
                                                   int* __restrict__ rp,
                                                   int* __restrict__ btot, int n) {
    __shared__ int lds[1024];
    int t = threadIdx.x;
    int i = blockIdx.x * 1024 + t;
    int v = (i < n) ? cnt[i] : 0;
    lds[t] = v;
    __syncthreads();
    for (int off = 1; off < 1024; off <<= 1) {
        int u = (t >= off) ? lds[t - off] : 0;
        __syncthreads();
        lds[t] += u;
        __syncthreads();
    }
    if (i < n) rp[i] = lds[t] - v;  // local exclusive
    if (t == 1023) btot[blockIdx.x] = lds[1023];
}

__global__ __launch_bounds__(64) void scan_btot(int* __restrict__ btot) {
    int t = threadIdx.x;
    int v = (t < SNB) ? btot[t] : 0;
#pragma unroll
    for (int off = 1; off < 64; off <<= 1) {
        int u = __shfl_up(v, off, 64);
        if (t >= off) v += u;
    }
    if (t < SNB) btot[t] = v;  // inclusive prefix
}

__global__ __launch_bounds__(1024) void scan_add(int* __restrict__ rp,
                                                 const int* __restrict__ btot, int n) {
    int b = blockIdx.x;
    int i = b * 1024 + threadIdx.x;
    int add = (b == 0) ? 0 : btot[b - 1];
    if (i < n) rp[i] += add;
    if (i == 0) rp[n] = EE;
}

__global__ void fill_pass(const int* __restrict__ ei, const int* __restrict__ row_ptr,
                          const int* __restrict__ slot, int* __restrict__ col, int ne) {
    int i = blockIdx.x * blockDim.x + threadIdx.x;
    if (i < ne) {
        int d = ei[ne + i];
        col[row_ptr[d] + slot[i]] = ei[i];
    }
}

// ---------------- fused GAT aggregate + bias + layernorm + residual relu
// wave per node; 8-edge-parallel: lane = eg(0..7)*8 + g(0..7);
// lane owns 16 channels [g*16, g*16+16), head = g>>1.
__global__ __launch_bounds__(256) void gat_aggregate(
    const ushort* __restrict__ xh, const float* __restrict__ ssrc,
    const float* __restrict__ sdst, const int* __restrict__ row_ptr,
    const int* __restrict__ col, const float* __restrict__ bg,
    const float* __restrict__ lng, const float* __restrict__ lnb,
    ushort* __restrict__ h, int n) {
    int wid = threadIdx.x >> 6;
    int lane = threadIdx.x & 63;
    int node = blockIdx.x * 4 + wid;
    if (node >= n) return;

    int base = row_ptr[node];
    int deg = row_ptr[node + 1] - base;

    float4 sd = ((const float4*)sdst)[node];
    float4 ssf = ((const float4*)ssrc)[node];

    int eg = lane >> 3;   // edge group 0..7
    int g = lane & 7;     // channel group; 16 channels
    int head = g >> 1;
    float sdH = pick4(head, sd.x, sd.y, sd.z, sd.w);
    float esH = lrelu(pick4(head, ssf.x, ssf.y, ssf.z, ssf.w) + sdH);

    float acc[16];
#pragma unroll
    for (int k = 0; k < 16; k++) acc[k] = 0.f;
    float z = 0.f;

    if (eg == 0) {  // self-loop once
        float w = fexp(esH);
        z = w;
        const short8* xr = (const short8*)(xh + (size_t)node * 128 + g * 16);
        short8 x0 = xr[0], x1 = xr[1];
#pragma unroll
        for (int k = 0; k < 8; k++) {
            acc[k] += w * bf2f((ushort)x0[k]);
            acc[k + 8] += w * bf2f((ushort)x1[k]);
        }
    }

    int nit = (deg + 7) >> 3;
#pragma unroll 2
    for (int t = 0; t < nit; t++) {
        int j = t * 8 + eg;
        if (j < deg) {
            int s = col[base + j];
            float4 ss = ((const float4*)ssrc)[s];
            float sH = pick4(head, ss.x, ss.y, ss.z, ss.w);
            float w = fexp(lrelu(sH + sdH));
            z += w;
            const short8* xr = (const short8*)(xh + (size_t)s * 128 + g * 16);
            short8 x0 = xr[0], x1 = xr[1];
#pragma unroll
            for (int k = 0; k < 8; k++) {
                acc[k] += w * bf2f((ushort)x0[k]);
                acc[k + 8] += w * bf2f((ushort)x1[k]);
            }
        }
    }
    // reduce across the 8 edge groups (lanes differing in bits 3,4,5)
#pragma unroll
    for (int k = 0; k < 16; k++) {
        acc[k] += __shfl_xor(acc[k], 8, 64);
        acc[k] += __shfl_xor(acc[k], 16, 64);
        acc[k] += __shfl_xor(acc[k], 32, 64);
    }
    z += __shfl_xor(z, 8, 64);
    z += __shfl_xor(z, 16, 64);
    z += __shfl_xor(z, 32, 64);
    float iz = 1.f / (z + 1e-16f);

    // bias + layernorm (channels replicated 8x across wave -> /1024)
    const float4* bg4 = (const float4*)(bg + g * 16);
    float o[16];
#pragma unroll
    for (int q = 0; q < 4; q++) {
        float4 b = bg4[q];
        o[q * 4 + 0] = acc[q * 4 + 0] * iz + b.x;
        o[q * 4 + 1] = acc[q * 4 + 1] * iz + b.y;
        o[q * 4 + 2] = acc[q * 4 + 2] * iz + b.z;
        o[q * 4 + 3] = acc[q * 4 + 3] * iz + b.w;
    }

    float ls = 0.f;
#pragma unroll
    for (int k = 0; k < 16; k++) ls += o[k];
    float mu = wred_sum(ls) * (1.f / 1024.f);
    float vs = 0.f;
#pragma unroll
    for (int k = 0; k < 16; k++) {
        o[k] -= mu;
        vs += o[k] * o[k];
    }
    float var = wred_sum(vs) * (1.f / 1024.f);
    float rs = rsqrtf(var + 1e-5f);

    if (eg == 0) {
        const float4* lg4 = (const float4*)(lng + g * 16);
        const float4* lb4 = (const float4*)(lnb + g * 16);
        ushort* hr = h + (size_t)node * 128 + g * 16;
        short8 prev0 = ((const short8*)hr)[0];
        short8 prev1 = ((const short8*)hr)[1];
        short8 ob0, ob1;
#pragma unroll
        for (int q = 0; q < 2; q++) {
            float4 gg = lg4[q];
            float4 qq = lb4[q];
            float y0 = fmaxf(o[q * 4 + 0] * rs * gg.x + qq.x + bf2f((ushort)prev0[q * 4 + 0]), 0.f);
            float y1 = fmaxf(o[q * 4 + 1] * rs * gg.y + qq.y + bf2f((ushort)prev0[q * 4 + 1]), 0.f);
            float y2 = fmaxf(o[q * 4 + 2] * rs * gg.z + qq.z + bf2f((ushort)prev0[q * 4 + 2]), 0.f);
            float y3 = fmaxf(o[q * 4 + 3] * rs * gg.w + qq.w + bf2f((ushort)prev0[q * 4 + 3]), 0.f);
            ob0[q * 4 + 0] = (short)f2bf(y0); ob0[q * 4 + 1] = (short)f2bf(y1);
            ob0[q * 4 + 2] = (short)f2bf(y2); ob0[q * 4 + 3] = (short)f2bf(y3);
        }
#pragma unroll
        for (int q = 0; q < 2; q++) {
            float4 gg = lg4[q + 2];
            float4 qq = lb4[q + 2];
            float y0 = fmaxf(o[8 + q * 4 + 0] * rs * gg.x + qq.x + bf2f((ushort)prev1[q * 4 + 0]), 0.f);
            float y1 = fmaxf(o[8 + q * 4 + 1] * rs * gg.y + qq.y + bf2f((ushort)prev1[q * 4 + 1]), 0.f);
            float y2 = fmaxf(o[8 + q * 4 + 2] * rs * gg.z + qq.z + bf2f((ushort)prev1[q * 4 + 2]), 0.f);
            float y3 = fmaxf(o[8 + q * 4 + 3] * rs * gg.w + qq.w + bf2f((ushort)prev1[q * 4 + 3]), 0.f);
            ob1[q * 4 + 0] = (short)f2bf(y0); ob1[q * 4 + 1] = (short)f2bf(y1);
            ob1[q * 4 + 2] = (short)f2bf(y2); ob1[q * 4 + 3] = (short)f2bf(y3);
        }
        ((short8*)hr)[0] = ob0;
        ((short8*)hr)[1] = ob1;
    }
}

// ---------------- mean pool (batch sorted -> run-length atomics), bf16 h
__global__ __launch_bounds__(256) void pool_kernel(const ushort* __restrict__ h,
                                                   const int* __restrict__ batch,
                                                   float* __restrict__ sums,
                                                   int* __restrict__ cnts, int n) {
    int c = threadIdx.x & 127;
    int half = threadIdx.x >> 7;
    int n0 = blockIdx.x * 64;
    float acc = 0.f;
    int cur = -1;
    for (int idx = half; idx < 64; idx += 2) {
        int node = n0 + idx;
        if (node >= n) break;
        int g = batch[node];
        if (g != cur) {
            if (cur >= 0) atomicAdd(&sums[cur * 128 + c], acc);
            cur = g;
            acc = 0.f;
        }
        acc += bf2f(h[(size_t)node * 128 + c]);
    }
    if (cur >= 0) atomicAdd(&sums[cur * 128 + c], acc);

    if (c == 0) {
        int cnt = 0, curg = -1;
        for (int idx = half; idx < 64; idx += 2) {
            int node = n0 + idx;
            if (node >= n) break;
            int g = batch[node];
            if (g != curg) {
                if (curg >= 0) atomicAdd(&cnts[curg], cnt);
                curg = g;
                cnt = 0;
            }
            cnt++;
        }
        if (curg >= 0) atomicAdd(&cnts[curg], cnt);
    }
}

// ---------------- MLP head: one block per graph
__global__ __launch_bounds__(256) void head_kernel(
    const float* __restrict__ sums, const int* __restrict__ cnts,
    const float* __restrict__ W1, const float* __restrict__ b1,
    const float* __restrict__ W2, const float* __restrict__ b2,
    const float* __restrict__ W3, const float* __restrict__ b3,
    float* __restrict__ out) {
    __shared__ float hg[128], z1[256], z2[128];
    int g = blockIdx.x;
    int t = threadIdx.x;
    if (t < 128) hg[t] = sums[g * 128 + t] / fmaxf((float)cnts[g], 1.f);
    __syncthreads();
    {
        float acc = b1[t];
        for (int k = 0; k < 128; k++) acc += hg[k] * W1[k * 256 + t];
        z1[t] = fmaxf(acc, 0.f);
    }
    __syncthreads();
    if (t < 128) {
        float acc = b2[t];
        for (int k = 0; k < 256; k++) acc += z1[k] * W2[k * 128 + t];
        z2[t] = fmaxf(acc, 0.f);
    }
    __syncthreads();
    if (t < NCLS) {
        float acc = b3[t];
        for (int k = 0; k < 128; k++) acc += z2[k] * W3[k * NCLS + t];
        out[g * NCLS + t] = acc;
    }
}

extern "C" void kernel_launch(void* const* d_in, const int* in_sizes, int n_in,
                              void* d_out, int out_size, void* d_ws, size_t ws_size,
                              hipStream_t stream) {
    const float* x = (const float*)d_in[0];
    const int* ei = (const int*)d_in[1];
    const int* ntypes = (const int*)d_in[2];
    const int* batch = (const int*)d_in[3];
    const float* W_node = (const float*)d_in[4];
    const float* b_node = (const float*)d_in[5];
    const float* temb = (const float*)d_in[6];
    const float* W_gat = (const float*)d_in[7];
    const float* a_src = (const float*)d_in[8];
    const float* a_dst = (const float*)d_in[9];
    const float* b_gat = (const float*)d_in[10];
    const float* ln_g = (const float*)d_in[11];
    const float* ln_b = (const float*)d_in[12];
    const float* W1 = (const float*)d_in[13];
    const float* b1 = (const float*)d_in[14];
    const float* W2 = (const float*)d_in[15];
    const float* b2 = (const float*)d_in[16];
    const float* W3 = (const float*)d_in[17];
    const float* b3 = (const float*)d_in[18];
    float* out = (float*)d_out;

    char* ws = (char*)d_ws;
    size_t off = 0;
    auto alloc = [&](size_t bytes) {
        void* p = ws + off;
        off += (bytes + 255) & ~(size_t)255;
        return p;
    };
    ushort* hb = (ushort*)alloc((size_t)NN * 128 * 2);   // bf16 h
    ushort* xhb = (ushort*)alloc((size_t)NN * 128 * 2);  // bf16 xh; aliases x_bf16
    ushort* WT = (ushort*)alloc((size_t)4 * 16384 * 2);
    float* ssrc = (float*)alloc((size_t)NN * 4 * 4);
    float* sdst = (float*)alloc((size_t)NN * 4 * 4);
    int* rowp = (int*)alloc((size_t)(NN + 1) * 4);
    int* fillc = (int*)alloc((size_t)NN * 4);
    int* col = (int*)alloc((size_t)EE * 4);
    int* slot = (int*)alloc((size_t)EE * 4);
    float* psum = (float*)alloc((size_t)NGRAPH * 128 * 4);
    int* pcnt = (int*)alloc((size_t)NGRAPH * 4);
    int* btot = (int*)alloc((size_t)SNB * 4);

    hipError_t e0;
    e0 = hipMemsetAsync(fillc, 0, (size_t)NN * 4, stream); (void)e0;
    e0 = hipMemsetAsync(psum, 0, (size_t)NGRAPH * 128 * 4, stream); (void)e0;
    e0 = hipMemsetAsync(pcnt, 0, (size_t)NGRAPH * 4, stream); (void)e0;

    // prep: x -> bf16 (into xhb), weights -> W^T bf16 swizzled
    convert_x<<<3125, 256, 0, stream>>>(x, xhb);
    prep_weights<<<4, 256, 0, stream>>>(W_node, W_gat, WT);

    // CSR build: count+slot -> scan -> non-atomic fill
    count_slot<<<(EE + 255) / 256, 256, 0, stream>>>(ei + EE, fillc, slot, EE);
    scan_local<<<SNB, 1024, 0, stream>>>(fillc, rowp, btot, NN);
    scan_btot<<<1, 64, 0, stream>>>(btot);
    scan_add<<<SNB, 1024, 0, stream>>>(rowp, btot, NN);
    fill_pass<<<(EE + 255) / 256, 256, 0, stream>>>(ei, rowp, slot, col, EE);

    // node init: h = x@W_node + b_node + temb[ntypes]  (bf16)
    int gemm_grid = (NN + 63) / 64;
    gemm_mfma<1><<<gemm_grid, 256, 0, stream>>>(xhb, WT, hb, b_node, ntypes, temb, NN);

    for (int l = 0; l < LL; l++) {
        gemm_mfma<0><<<gemm_grid, 256, 0, stream>>>(hb, WT + (size_t)(l + 1) * 16384, xhb,
                                                    nullptr, nullptr, nullptr, NN);
        attn_scores<<<(NN + 15) / 16, 256, 0, stream>>>(xhb, a_src + l * HEADS * CC,
                                                        a_dst + l * HEADS * CC, ssrc, sdst, NN);
        gat_aggregate<<<(NN + 3) / 4, 256, 0, stream>>>(
            xhb, ssrc, sdst, rowp, col, b_gat + l * 128, ln_g + l * 128, ln_b + l * 128,
            hb, NN);
    }

    pool_kernel<<<(NN + 63) / 64, 256, 0, stream>>>(hb, batch, psum, pcnt, NN);
    head_kernel<<<NGRAPH, 256, 0, stream>>>(psum, pcnt, W1, b1, W2, b2, W3, b3, out);
}

// Round 10
// 332.541 us; speedup vs baseline: 3.5570x; 1.0438x over previous
//
#include <hip/hip_runtime.h>
#include <hip/hip_bf16.h>

#define NN 50000
#define EE 800000
#define IN_DIM 128
#define HH 128
#define HEADS 4
#define CC 32
#define LL 3
#define NCLS 10
#define NGRAPH 64
#define SNB ((NN + 1023) / 1024)  // 49 scan blocks

using short8 = __attribute__((ext_vector_type(8))) short;
using f32x4 = __attribute__((ext_vector_type(4))) float;

__device__ inline float lrelu(float x) { return fmaxf(x, 0.2f * x); }
__device__ inline float fexp(float x) { return __expf(x); }

__device__ inline float bf2f(ushort u) {
    union { uint32_t i; float f; } c;
    c.i = ((uint32_t)u) << 16;
    return c.f;
}
__device__ inline ushort f2bf(float f) {
    union { float f; uint32_t i; } c;
    c.f = f;
    uint32_t x = c.i;
    uint32_t r = (x + 0x7fffu + ((x >> 16) & 1u)) >> 16;
    return (ushort)r;
}

__device__ inline float wred_sum(float v) {
#pragma unroll
    for (int m = 32; m >= 1; m >>= 1) v += __shfl_xor(v, m, 64);
    return v;
}

__device__ inline float pick4(int h, float a, float b, float c, float d) {
    float ab = (h & 1) ? b : a;
    float cd = (h & 1) ? d : c;
    return (h & 2) ? cd : ab;
}

// ---------------- x -> bf16 (6.4M elements, 8/thread)
__global__ __launch_bounds__(256) void convert_x(const float* __restrict__ x,
                                                 ushort* __restrict__ xb) {
    int u = blockIdx.x * 256 + threadIdx.x;  // ushort8 unit
    const float4* x4 = (const float4*)x;
    float4 f0 = x4[u * 2];
    float4 f1 = x4[u * 2 + 1];
    short8 o;
    o[0] = (short)f2bf(f0.x); o[1] = (short)f2bf(f0.y);
    o[2] = (short)f2bf(f0.z); o[3] = (short)f2bf(f0.w);
    o[4] = (short)f2bf(f1.x); o[5] = (short)f2bf(f1.y);
    o[6] = (short)f2bf(f1.z); o[7] = (short)f2bf(f1.w);
    ((short8*)xb)[u] = o;
}

// ---------------- weights -> W^T bf16, pre-swizzled (16B unit u ^= n&7)
__global__ __launch_bounds__(256) void prep_weights(const float* __restrict__ W_node,
                                                    const float* __restrict__ W_gat,
                                                    ushort* __restrict__ WT) {
    int b = blockIdx.x;
    const float* W = (b == 0) ? W_node : (W_gat + (size_t)(b - 1) * 16384);
    ushort* D = WT + (size_t)b * 16384;
    int t = threadIdx.x;
    int n = t >> 1;
    int k0 = (t & 1) * 64;
    for (int kk = 0; kk < 64; kk++) {
        int k = k0 + kk;
        float v = W[k * 128 + n];
        int u = (k >> 3) ^ (n & 7);
        D[n * 128 + u * 8 + (k & 7)] = f2bf(v);
    }
}

// ---------------- MFMA GEMM: out_bf[N,128] = A_bf16[N,128] @ W
template <int MODE>
__global__ __launch_bounds__(256) void gemm_mfma(
    const ushort* __restrict__ Abf, const ushort* __restrict__ WT,
    ushort* __restrict__ out_bf,
    const float* __restrict__ bias, const int* __restrict__ ntypes,
    const float* __restrict__ temb, int nrows) {
    __shared__ ushort wlds[16384];
    int tid = threadIdx.x;
    int lane = tid & 63;
    int wid = tid >> 6;

    {
        const short8* src = (const short8*)WT;
        short8* dst = (short8*)wlds;
#pragma unroll
        for (int i = 0; i < 8; i++) dst[i * 256 + tid] = src[i * 256 + tid];
    }

    int rbase = blockIdx.x * 64 + wid * 16;
    int arow = rbase + (lane & 15);
    if (arow >= nrows) arow = nrows - 1;
    const short8* arow_p = (const short8*)(Abf + (size_t)arow * 128);
    short8 afr[4];
#pragma unroll
    for (int ks = 0; ks < 4; ks++) afr[ks] = arow_p[ks * 4 + (lane >> 4)];

    __syncthreads();

    f32x4 acc[8];
#pragma unroll
    for (int i = 0; i < 8; i++) acc[i] = (f32x4){0.f, 0.f, 0.f, 0.f};

    int cgrp = lane & 15;
    int kgrp = lane >> 4;
#pragma unroll
    for (int ks = 0; ks < 4; ks++) {
        short8 a = afr[ks];
#pragma unroll
        for (int nt = 0; nt < 8; nt++) {
            int n = nt * 16 + cgrp;
            int u = (ks * 4 + kgrp) ^ (n & 7);
            short8 b = *(const short8*)&wlds[n * 128 + u * 8];
            acc[nt] = __builtin_amdgcn_mfma_f32_16x16x32_bf16(a, b, acc[nt], 0, 0, 0);
        }
    }

    int nts[4];
    if (MODE == 1) {
#pragma unroll
        for (int r = 0; r < 4; r++) {
            int row = rbase + kgrp * 4 + r;
            nts[r] = (row < nrows) ? ntypes[row] : 0;
        }
    }
#pragma unroll
    for (int nt = 0; nt < 8; nt++) {
        int colc = nt * 16 + cgrp;
#pragma unroll
        for (int r = 0; r < 4; r++) {
            int row = rbase + kgrp * 4 + r;
            if (row < nrows) {
                float v = acc[nt][r];
                if (MODE == 1) v += bias[colc] + temb[nts[r] * 128 + colc];
                out_bf[(size_t)row * 128 + colc] = f2bf(v);
            }
        }
    }
}

// ---------------- per-node attention scores s_src/s_dst [N,4]
__global__ __launch_bounds__(256) void attn_scores(
    const ushort* __restrict__ xh, const float* __restrict__ asrc,
    const float* __restrict__ adst, float* __restrict__ s_src,
    float* __restrict__ s_dst, int n) {
    int tid = threadIdx.x;
    int node = blockIdx.x * 16 + (tid >> 4);
    int g = tid & 15;
    if (node >= n) return;
    short8 xv = *(const short8*)(xh + (size_t)node * 128 + g * 8);
    const float4* as4 = (const float4*)(asrc + g * 8);
    const float4* ad4 = (const float4*)(adst + g * 8);
    float4 a0 = as4[0], a1 = as4[1];
    float4 d0 = ad4[0], d1 = ad4[1];
    float xf[8];
#pragma unroll
    for (int k = 0; k < 8; k++) xf[k] = bf2f((ushort)xv[k]);
    float ps = xf[0] * a0.x + xf[1] * a0.y + xf[2] * a0.z + xf[3] * a0.w +
               xf[4] * a1.x + xf[5] * a1.y + xf[6] * a1.z + xf[7] * a1.w;
    float pd = xf[0] * d0.x + xf[1] * d0.y + xf[2] * d0.z + xf[3] * d0.w +
               xf[4] * d1.x + xf[5] * d1.y + xf[6] * d1.z + xf[7] * d1.w;
    ps += __shfl_xor(ps, 1, 64); ps += __shfl_xor(ps, 2, 64);
    pd += __shfl_xor(pd, 1, 64); pd += __shfl_xor(pd, 2, 64);
    if ((g & 3) == 0) {
        s_src[node * 4 + (g >> 2)] = ps;
        s_dst[node * 4 + (g >> 2)] = pd;
    }
}

// ---------------- CSR build: pass A = count + slot, pass B = non-atomic fill
__global__ void count_slot(const int* __restrict__ dst, int* __restrict__ deg,
                           int* __restrict__ slot, int ne) {
    int i = blockIdx.x * blockDim.x + threadIdx.x;
    if (i < ne) slot[i] = atomicAdd(&deg[dst[i]], 1);
}

__global__ __launch_bounds__(1024) void scan_local(const int* __restrict__ cnt,
                                                   int* __restrict__ rp,
                                                   int* __restrict__ btot, int n) {
    __shared__ int lds[1024];
    int t = threadIdx.x;
    int i = blockIdx.x * 1024 + t;
    int v = (i < n) ? cnt[i] : 0;
    lds[t] = v;
    __syncthreads();
    for (int off = 1; off < 1024; off <<= 1) {
        int u = (t >= off) ? lds[t - off] : 0;
        __syncthreads();
        lds[t] += u;
        __syncthreads();
    }
    if (i < n) rp[i] = lds[t] - v;  // local exclusive
    if (t == 1023) btot[blockIdx.x] = lds[1023];
}

__global__ __launch_bounds__(64) void scan_btot(int* __restrict__ btot) {
    int t = threadIdx.x;
    int v = (t < SNB) ? btot[t] : 0;
#pragma unroll
    for (int off = 1; off < 64; off <<= 1) {
        int u = __shfl_up(v, off, 64);
        if (t >= off) v += u;
    }
    if (t < SNB) btot[t] = v;  // inclusive prefix
}

__global__ __launch_bounds__(1024) void scan_add(int* __restrict__ rp,
                                                 const int* __restrict__ btot, int n) {
    int b = blockIdx.x;
    int i = b * 1024 + threadIdx.x;
    int add = (b == 0) ? 0 : btot[b - 1];
    if (i < n) rp[i] += add;
    if (i == 0) rp[n] = EE;
}

__global__ void fill_pass(const int* __restrict__ ei, const int* __restrict__ row_ptr,
                          const int* __restrict__ slot, int* __restrict__ col, int ne) {
    int i = blockIdx.x * blockDim.x + threadIdx.x;
    if (i < ne) {
        int d = ei[ne + i];
        col[row_ptr[d] + slot[i]] = ei[i];
    }
}

// ---------------- fused GAT aggregate + bias + layernorm + residual relu
// wave per node; 4-edge-parallel: lane = eg(0..3)*16 + g(0..15);
// lane owns 8 channels [g*8, g*8+8), head = g>>2. (round-7 proven layout)
__global__ __launch_bounds__(256) void gat_aggregate(
    const ushort* __restrict__ xh, const float* __restrict__ ssrc,
    const float* __restrict__ sdst, const int* __restrict__ row_ptr,
    const int* __restrict__ col, const float* __restrict__ bg,
    const float* __restrict__ lng, const float* __restrict__ lnb,
    ushort* __restrict__ h, int n) {
    int wid = threadIdx.x >> 6;
    int lane = threadIdx.x & 63;
    int node = blockIdx.x * 4 + wid;
    if (node >= n) return;

    int base = row_ptr[node];
    int deg = row_ptr[node + 1] - base;

    float4 sd = ((const float4*)sdst)[node];
    float4 ssf = ((const float4*)ssrc)[node];

    int eg = lane >> 4;
    int g = lane & 15;
    int head = g >> 2;
    float sdH = pick4(head, sd.x, sd.y, sd.z, sd.w);
    float esH = lrelu(pick4(head, ssf.x, ssf.y, ssf.z, ssf.w) + sdH);

    float acc[8];
#pragma unroll
    for (int k = 0; k < 8; k++) acc[k] = 0.f;
    float z = 0.f;

    if (eg == 0) {  // self-loop once
        float w = fexp(esH);
        z = w;
        short8 xv = *(const short8*)(xh + (size_t)node * 128 + g * 8);
#pragma unroll
        for (int k = 0; k < 8; k++) acc[k] += w * bf2f((ushort)xv[k]);
    }

    int nit = (deg + 3) >> 2;
#pragma unroll 2
    for (int t = 0; t < nit; t++) {
        int j = t * 4 + eg;
        if (j < deg) {
            int s = col[base + j];
            float4 ss = ((const float4*)ssrc)[s];
            float sH = pick4(head, ss.x, ss.y, ss.z, ss.w);
            float w = fexp(lrelu(sH + sdH));
            z += w;
            short8 xv = *(const short8*)(xh + (size_t)s * 128 + g * 8);
#pragma unroll
            for (int k = 0; k < 8; k++) acc[k] += w * bf2f((ushort)xv[k]);
        }
    }
#pragma unroll
    for (int k = 0; k < 8; k++) {
        acc[k] += __shfl_xor(acc[k], 16, 64);
        acc[k] += __shfl_xor(acc[k], 32, 64);
    }
    z += __shfl_xor(z, 16, 64);
    z += __shfl_xor(z, 32, 64);
    float iz = 1.f / (z + 1e-16f);

    // bias + layernorm (channels replicated 4x across wave -> /512)
    const float4* bg4 = (const float4*)(bg + g * 8);
    float4 b0 = bg4[0], b1 = bg4[1];
    float o[8];
    o[0] = acc[0] * iz + b0.x; o[1] = acc[1] * iz + b0.y;
    o[2] = acc[2] * iz + b0.z; o[3] = acc[3] * iz + b0.w;
    o[4] = acc[4] * iz + b1.x; o[5] = acc[5] * iz + b1.y;
    o[6] = acc[6] * iz + b1.z; o[7] = acc[7] * iz + b1.w;

    float ls = 0.f;
#pragma unroll
    for (int k = 0; k < 8; k++) ls += o[k];
    float mu = wred_sum(ls) * (1.f / 512.f);
    float vs = 0.f;
#pragma unroll
    for (int k = 0; k < 8; k++) {
        o[k] -= mu;
        vs += o[k] * o[k];
    }
    float var = wred_sum(vs) * (1.f / 512.f);
    float rs = rsqrtf(var + 1e-5f);

    if (eg == 0) {
        const float4* lg4 = (const float4*)(lng + g * 8);
        const float4* lb4 = (const float4*)(lnb + g * 8);
        float4 g0 = lg4[0], g1 = lg4[1];
        float4 q0 = lb4[0], q1 = lb4[1];
        ushort* hr = h + (size_t)node * 128 + g * 8;
        short8 prev = *(const short8*)hr;
        float y[8];
        y[0] = fmaxf(o[0] * rs * g0.x + q0.x + bf2f((ushort)prev[0]), 0.f);
        y[1] = fmaxf(o[1] * rs * g0.y + q0.y + bf2f((ushort)prev[1]), 0.f);
        y[2] = fmaxf(o[2] * rs * g0.z + q0.z + bf2f((ushort)prev[2]), 0.f);
        y[3] = fmaxf(o[3] * rs * g0.w + q0.w + bf2f((ushort)prev[3]), 0.f);
        y[4] = fmaxf(o[4] * rs * g1.x + q1.x + bf2f((ushort)prev[4]), 0.f);
        y[5] = fmaxf(o[5] * rs * g1.y + q1.y + bf2f((ushort)prev[5]), 0.f);
        y[6] = fmaxf(o[6] * rs * g1.z + q1.z + bf2f((ushort)prev[6]), 0.f);
        y[7] = fmaxf(o[7] * rs * g1.w + q1.w + bf2f((ushort)prev[7]), 0.f);
        short8 ob;
#pragma unroll
        for (int k = 0; k < 8; k++) ob[k] = (short)f2bf(y[k]);
        *(short8*)hr = ob;
    }
}

// ---------------- mean pool (batch sorted -> run-length atomics), bf16 h
__global__ __launch_bounds__(256) void pool_kernel(const ushort* __restrict__ h,
                                                   const int* __restrict__ batch,
                                                   float* __restrict__ sums,
                                                   int* __restrict__ cnts, int n) {
    int c = threadIdx.x & 127;
    int half = threadIdx.x >> 7;
    int n0 = blockIdx.x * 64;
    float acc = 0.f;
    int cur = -1;
    for (int idx = half; idx < 64; idx += 2) {
        int node = n0 + idx;
        if (node >= n) break;
        int g = batch[node];
        if (g != cur) {
            if (cur >= 0) atomicAdd(&sums[cur * 128 + c], acc);
            cur = g;
            acc = 0.f;
        }
        acc += bf2f(h[(size_t)node * 128 + c]);
    }
    if (cur >= 0) atomicAdd(&sums[cur * 128 + c], acc);

    if (c == 0) {
        int cnt = 0, curg = -1;
        for (int idx = half; idx < 64; idx += 2) {
            int node = n0 + idx;
            if (node >= n) break;
            int g = batch[node];
            if (g != curg) {
                if (curg >= 0) atomicAdd(&cnts[curg], cnt);
                curg = g;
                cnt = 0;
            }
            cnt++;
        }
        if (curg >= 0) atomicAdd(&cnts[curg], cnt);
    }
}

// ---------------- MLP head: one block per graph
__global__ __launch_bounds__(256) void head_kernel(
    const float* __restrict__ sums, const int* __restrict__ cnts,
    const float* __restrict__ W1, const float* __restrict__ b1,
    const float* __restrict__ W2, const float* __restrict__ b2,
    const float* __restrict__ W3, const float* __restrict__ b3,
    float* __restrict__ out) {
    __shared__ float hg[128], z1[256], z2[128];
    int g = blockIdx.x;
    int t = threadIdx.x;
    if (t < 128) hg[t] = sums[g * 128 + t] / fmaxf((float)cnts[g], 1.f);
    __syncthreads();
    {
        float acc = b1[t];
        for (int k = 0; k < 128; k++) acc += hg[k] * W1[k * 256 + t];
        z1[t] = fmaxf(acc, 0.f);
    }
    __syncthreads();
    if (t < 128) {
        float acc = b2[t];
        for (int k = 0; k < 256; k++) acc += z1[k] * W2[k * 128 + t];
        z2[t] = fmaxf(acc, 0.f);
    }
    __syncthreads();
    if (t < NCLS) {
        float acc = b3[t];
        for (int k = 0; k < 128; k++) acc += z2[k] * W3[k * NCLS + t];
        out[g * NCLS + t] = acc;
    }
}

extern "C" void kernel_launch(void* const* d_in, const int* in_sizes, int n_in,
                              void* d_out, int out_size, void* d_ws, size_t ws_size,
                              hipStream_t stream) {
    const float* x = (const float*)d_in[0];
    const int* ei = (const int*)d_in[1];
    const int* ntypes = (const int*)d_in[2];
    const int* batch = (const int*)d_in[3];
    const float* W_node = (const float*)d_in[4];
    const float* b_node = (const float*)d_in[5];
    const float* temb = (const float*)d_in[6];
    const float* W_gat = (const float*)d_in[7];
    const float* a_src = (const float*)d_in[8];
    const float* a_dst = (const float*)d_in[9];
    const float* b_gat = (const float*)d_in[10];
    const float* ln_g = (const float*)d_in[11];
    const float* ln_b = (const float*)d_in[12];
    const float* W1 = (const float*)d_in[13];
    const float* b1 = (const float*)d_in[14];
    const float* W2 = (const float*)d_in[15];
    const float* b2 = (const float*)d_in[16];
    const float* W3 = (const float*)d_in[17];
    const float* b3 = (const float*)d_in[18];
    float* out = (float*)d_out;

    char* ws = (char*)d_ws;
    size_t off = 0;
    auto alloc = [&](size_t bytes) {
        void* p = ws + off;
        off += (bytes + 255) & ~(size_t)255;
        return p;
    };
    ushort* hb = (ushort*)alloc((size_t)NN * 128 * 2);   // bf16 h
    ushort* xhb = (ushort*)alloc((size_t)NN * 128 * 2);  // bf16 xh; aliases x_bf16
    ushort* WT = (ushort*)alloc((size_t)4 * 16384 * 2);
    float* ssrc = (float*)alloc((size_t)NN * 4 * 4);
    float* sdst = (float*)alloc((size_t)NN * 4 * 4);
    int* rowp = (int*)alloc((size_t)(NN + 1) * 4);
    int* fillc = (int*)alloc((size_t)NN * 4);
    int* col = (int*)alloc((size_t)EE * 4);
    int* slot = (int*)alloc((size_t)EE * 4);
    float* psum = (float*)alloc((size_t)NGRAPH * 128 * 4);
    int* pcnt = (int*)alloc((size_t)NGRAPH * 4);
    int* btot = (int*)alloc((size_t)SNB * 4);

    hipError_t e0;
    e0 = hipMemsetAsync(fillc, 0, (size_t)NN * 4, stream); (void)e0;
    e0 = hipMemsetAsync(psum, 0, (size_t)NGRAPH * 128 * 4, stream); (void)e0;
    e0 = hipMemsetAsync(pcnt, 0, (size_t)NGRAPH * 4, stream); (void)e0;

    // prep: x -> bf16 (into xhb), weights -> W^T bf16 swizzled
    convert_x<<<3125, 256, 0, stream>>>(x, xhb);
    prep_weights<<<4, 256, 0, stream>>>(W_node, W_gat, WT);

    // CSR build: count+slot -> scan -> non-atomic fill
    count_slot<<<(EE + 255) / 256, 256, 0, stream>>>(ei + EE, fillc, slot, EE);
    scan_local<<<SNB, 1024, 0, stream>>>(fillc, rowp, btot, NN);
    scan_btot<<<1, 64, 0, stream>>>(btot);
    scan_add<<<SNB, 1024, 0, stream>>>(rowp, btot, NN);
    fill_pass<<<(EE + 255) / 256, 256, 0, stream>>>(ei, rowp, slot, col, EE);

    // node init: h = x@W_node + b_node + temb[ntypes]  (bf16)
    int gemm_grid = (NN + 63) / 64;
    gemm_mfma<1><<<gemm_grid, 256, 0, stream>>>(xhb, WT, hb, b_node, ntypes, temb, NN);

    for (int l = 0; l < LL; l++) {
        gemm_mfma<0><<<gemm_grid, 256, 0, stream>>>(hb, WT + (size_t)(l + 1) * 16384, xhb,
                                                    nullptr, nullptr, nullptr, NN);
        attn_scores<<<(NN + 15) / 16, 256, 0, stream>>>(xhb, a_src + l * HEADS * CC,
                                                        a_dst + l * HEADS * CC, ssrc, sdst, NN);
        gat_aggregate<<<(NN + 3) / 4, 256, 0, stream>>>(
            xhb, ssrc, sdst, rowp, col, b_gat + l * 128, ln_g + l * 128, ln_b + l * 128,
            hb, NN);
    }

    pool_kernel<<<(NN + 63) / 64, 256, 0, stream>>>(hb, batch, psum, pcnt, NN);
    head_kernel<<<NGRAPH, 256, 0, stream>>>(psum, pcnt, W1, b1, W2, b2, W3, b3, out);
}